// Round 6
// baseline (2943.218 us; speedup 1.0000x reference)
//
#include <hip/hip_runtime.h>
#include <cstdint>
#include <cstddef>

// Problem constants (from reference)
#define NGg   128     // 2*B
#define Bb    64
#define Nn    48
#define Ee    192
#define Sdim  64
#define VNn   6144    // NGg*Nn
#define VEe   24576   // NGg*Ee
#define INV_TEMP 10.0f
#define ADJ_STRIDE 96

typedef unsigned short u16;
typedef unsigned int   u32;
typedef __attribute__((ext_vector_type(8))) short short8;
typedef __attribute__((ext_vector_type(4))) float floatx4;

// round-to-nearest-even fp32 -> bf16
__device__ __forceinline__ u16 f2bf(float f)
{
    unsigned int u = __float_as_uint(f);
    u += 0x7FFFu + ((u >> 16) & 1u);
    return (u16)(u >> 16);
}
__device__ __forceinline__ float bf2f(u16 h)
{
    return __uint_as_float(((unsigned int)h) << 16);
}

// Packed split-bf16 activation: u32 = hi_bf16 | (lo_bf16 << 16), v ~= hi+lo.
__device__ __forceinline__ u32 packhl(float v)
{
    u16 h = f2bf(v);
    u16 l = f2bf(v - bf2f(h));
    return (u32)h | ((u32)l << 16);
}
__device__ __forceinline__ float unpackhl(u32 w)
{
    return __uint_as_float(w << 16) + __uint_as_float(w & 0xFFFF0000u);
}

// flags bits
#define FL_RELU  1
#define FL_OUTPK 4
#define FL_MSGS  8   // msgs epilogue: pack(2*(acc+bias) + qs[f]+qs[t])

#define TW 40

// ---------------------------------------------------------------------------
// Split-precision bf16x3 MFMA GEMM, packed-hl A operand, templated tile.
// ---------------------------------------------------------------------------
template<int BM, int BN>
__global__ __launch_bounds__(256) void gemm_pk_kernel(
    const u32* __restrict__ A1, int lda1, int K1,
    const u32* __restrict__ A2, int lda2, int K2,
    const u16* __restrict__ Wh, const u16* __restrict__ Wl, int ldwt,
    const float* __restrict__ bias,
    void* __restrict__ Cv, int ldc,
    int Ncap, int flags)
{
    constexpr int FM = BM / 32;
    constexpr int FN = BN / 32;
    constexpr int NA = BM / 8;
    constexpr int NB = BN / 8;
    __shared__ __align__(16) u16 Ah[BM * TW];
    __shared__ __align__(16) u16 Al[BM * TW];
    __shared__ __align__(16) u16 Bh[BN * TW];
    __shared__ __align__(16) u16 Bl[BN * TW];
    const int tid = threadIdx.x;
    const int lane = tid & 63, wave = tid >> 6;
    const int wm = wave >> 1, wn = wave & 1;
    const int bm = blockIdx.y * BM, bn = blockIdx.x * BN;
    const int K = K1 + K2;
    const int AR  = (BM == 128) ? (tid >> 1) : (tid >> 2);
    const int AKo = (BM == 128) ? ((tid & 1) * 16) : ((tid & 3) * 8);
    const int BR  = (BN == 128) ? (tid >> 1) : (tid >> 2);
    const int BKo = (BN == 128) ? ((tid & 1) * 16) : ((tid & 3) * 8);
    const int arow = bm + AR;
    const int brow = bn + BR;
    const int l15 = lane & 15, lq = lane >> 4;

    floatx4 acc[FM][FN];
    #pragma unroll
    for (int i = 0; i < FM; i++)
        #pragma unroll
        for (int j = 0; j < FN; j++) acc[i][j] = (floatx4){0.f, 0.f, 0.f, 0.f};

    for (int k0 = 0; k0 < K; k0 += 32) {
        {
            const int kk = k0 + BKo;
            const u16* bh = Wh + (size_t)brow * ldwt + kk;
            const u16* bl = Wl + (size_t)brow * ldwt + kk;
            #pragma unroll
            for (int q = 0; q < NB / 8; q++) {
                *(uint4*)&Bh[BR * TW + BKo + q * 8] = ((const uint4*)bh)[q];
                *(uint4*)&Bl[BR * TW + BKo + q * 8] = ((const uint4*)bl)[q];
            }
        }
        {
            const int kk = k0 + AKo;
            const u32* asrc = (kk < K1) ? A1 + (size_t)arow * lda1 + kk
                                        : A2 + (size_t)arow * lda2 + (kk - K1);
            u32 pk[NA];
            #pragma unroll
            for (int q = 0; q < NA / 4; q++)
                ((uint4*)pk)[q] = ((const uint4*)asrc)[q];
            u32 hi[NA / 2], lo[NA / 2];
            #pragma unroll
            for (int q = 0; q < NA / 2; q++) {
                hi[q] = __builtin_amdgcn_perm(pk[2 * q + 1], pk[2 * q], 0x05040100u);
                lo[q] = __builtin_amdgcn_perm(pk[2 * q + 1], pk[2 * q], 0x07060302u);
            }
            #pragma unroll
            for (int q = 0; q < NA / 8; q++) {
                *(uint4*)&Ah[AR * TW + AKo + q * 8] = ((uint4*)hi)[q];
                *(uint4*)&Al[AR * TW + AKo + q * 8] = ((uint4*)lo)[q];
            }
        }
        __syncthreads();
        short8 afh[FM], afl[FM], bfh[FN], bfl[FN];
        #pragma unroll
        for (int i = 0; i < FM; i++) {
            const int ro = (wm * (BM / 2) + i * 16 + l15) * TW + lq * 8;
            afh[i] = *(const short8*)&Ah[ro];
            afl[i] = *(const short8*)&Al[ro];
        }
        #pragma unroll
        for (int j = 0; j < FN; j++) {
            const int ro = (wn * (BN / 2) + j * 16 + l15) * TW + lq * 8;
            bfh[j] = *(const short8*)&Bh[ro];
            bfl[j] = *(const short8*)&Bl[ro];
        }
        #pragma unroll
        for (int i = 0; i < FM; i++)
            #pragma unroll
            for (int j = 0; j < FN; j++) {
                acc[i][j] = __builtin_amdgcn_mfma_f32_16x16x32_bf16(afh[i], bfl[j], acc[i][j], 0, 0, 0);
                acc[i][j] = __builtin_amdgcn_mfma_f32_16x16x32_bf16(afl[i], bfh[j], acc[i][j], 0, 0, 0);
                acc[i][j] = __builtin_amdgcn_mfma_f32_16x16x32_bf16(afh[i], bfh[j], acc[i][j], 0, 0, 0);
            }
        __syncthreads();
    }
    const int relu = flags & FL_RELU;
    const int opk  = flags & FL_OUTPK;
    #pragma unroll
    for (int j = 0; j < FN; j++) {
        const int col = bn + wn * (BN / 2) + j * 16 + l15;
        const bool cok = (col < Ncap);
        const float bv = (bias && cok) ? bias[col] : 0.f;
        #pragma unroll
        for (int i = 0; i < FM; i++) {
            const int row0 = bm + wm * (BM / 2) + i * 16 + lq * 4;
            #pragma unroll
            for (int r = 0; r < 4; r++) {
                float v = acc[i][j][r] + bv;
                if (relu) v = fmaxf(v, 0.f);
                if (cok) {
                    if (opk)
                        ((u32*)Cv)[(size_t)(row0 + r) * ldc + col] = packhl(v);
                    else
                        ((float*)Cv)[(size_t)(row0 + r) * ldc + col] = v;
                }
            }
        }
    }
}

static inline void gemmPK(hipStream_t s, int BM, int BN,
                          const u32* A1, int lda1, int K1,
                          const u32* A2, int lda2, int K2,
                          const u16* Wh, const u16* Wl, int ldwt,
                          const float* bias,
                          void* C, int ldc, int M, int Ngrid, int Ncap, int flags)
{
    dim3 grid(Ngrid / BN, M / BM);
    if (BM == 128 && BN == 128)
        gemm_pk_kernel<128, 128><<<grid, 256, 0, s>>>(A1, lda1, K1, A2, lda2, K2, Wh, Wl, ldwt, bias, C, ldc, Ncap, flags);
    else if (BM == 128 && BN == 64)
        gemm_pk_kernel<128, 64><<<grid, 256, 0, s>>>(A1, lda1, K1, A2, lda2, K2, Wh, Wl, ldwt, bias, C, ldc, Ncap, flags);
    else if (BM == 64 && BN == 128)
        gemm_pk_kernel<64, 128><<<grid, 256, 0, s>>>(A1, lda1, K1, A2, lda2, K2, Wh, Wl, ldwt, bias, C, ldc, Ncap, flags);
    else
        gemm_pk_kernel<64, 64><<<grid, 256, 0, s>>>(A1, lda1, K1, A2, lda2, K2, Wh, Wl, ldwt, bias, C, ldc, Ncap, flags);
}

// ---------------------------------------------------------------------------
// Dual-GEMM fused dispatch (128x128 tiles), FL_MSGS epilogue variant kept.
// ---------------------------------------------------------------------------
struct GemmDesc {
    const u32* A1; int lda1, K1;
    const u32* A2; int lda2, K2;
    const u16* Wh; const u16* Wl; int ldwt;
    const float* bias;
    void* C; int ldc;
    int Ncap, flags, nx, nblk;
    const float* qs;            // FL_MSGS only
    const int* fidx; const int* tidx;
};

static inline GemmDesc mkDesc(const u32* A1, int lda1, int K1,
                              const u32* A2, int lda2, int K2,
                              const u16* Wh, const u16* Wl, int ldwt,
                              const float* bias, void* C, int ldc,
                              int M, int Ngrid, int Ncap, int flags)
{
    GemmDesc d;
    d.A1 = A1; d.lda1 = lda1; d.K1 = K1;
    d.A2 = A2; d.lda2 = lda2; d.K2 = K2;
    d.Wh = Wh; d.Wl = Wl; d.ldwt = ldwt;
    d.bias = bias; d.C = C; d.ldc = ldc;
    d.Ncap = Ncap; d.flags = flags;
    d.nx = Ngrid / 128; d.nblk = (M / 128) * (Ngrid / 128);
    d.qs = nullptr; d.fidx = nullptr; d.tidx = nullptr;
    return d;
}

__global__ __launch_bounds__(256) void gemm2_pk_kernel(GemmDesc d0, GemmDesc d1, int nb0)
{
    GemmDesc d;
    int local;
    if ((int)blockIdx.x < nb0) { d = d0; local = blockIdx.x; }
    else                       { d = d1; local = blockIdx.x - nb0; }
    const int by = local / d.nx, bx = local % d.nx;
    __shared__ __align__(16) u16 Ah[128 * TW];
    __shared__ __align__(16) u16 Al[128 * TW];
    __shared__ __align__(16) u16 Bh[128 * TW];
    __shared__ __align__(16) u16 Bl[128 * TW];
    const int tid = threadIdx.x;
    const int lane = tid & 63, wave = tid >> 6;
    const int wm = wave >> 1, wn = wave & 1;
    const int bm = by * 128, bn = bx * 128;
    const int K = d.K1 + d.K2;
    const int srow = tid >> 1;
    const int skoff = (tid & 1) * 16;
    const int arow = bm + srow;
    const int brow = bn + srow;
    const int l15 = lane & 15, lq = lane >> 4;

    floatx4 acc[4][4];
    #pragma unroll
    for (int i = 0; i < 4; i++)
        #pragma unroll
        for (int j = 0; j < 4; j++) acc[i][j] = (floatx4){0.f, 0.f, 0.f, 0.f};

    for (int k0 = 0; k0 < K; k0 += 32) {
        {
            const int kk = k0 + skoff;
            const u16* bh = d.Wh + (size_t)brow * d.ldwt + kk;
            const u16* bl = d.Wl + (size_t)brow * d.ldwt + kk;
            *(uint4*)&Bh[srow * TW + skoff]     = ((const uint4*)bh)[0];
            *(uint4*)&Bh[srow * TW + skoff + 8] = ((const uint4*)bh)[1];
            *(uint4*)&Bl[srow * TW + skoff]     = ((const uint4*)bl)[0];
            *(uint4*)&Bl[srow * TW + skoff + 8] = ((const uint4*)bl)[1];
        }
        {
            const int kk = k0 + skoff;
            const u32* asrc = (kk < d.K1) ? d.A1 + (size_t)arow * d.lda1 + kk
                                          : d.A2 + (size_t)arow * d.lda2 + (kk - d.K1);
            u32 pk[16];
            ((uint4*)pk)[0] = ((const uint4*)asrc)[0];
            ((uint4*)pk)[1] = ((const uint4*)asrc)[1];
            ((uint4*)pk)[2] = ((const uint4*)asrc)[2];
            ((uint4*)pk)[3] = ((const uint4*)asrc)[3];
            u32 hi[8], lo[8];
            #pragma unroll
            for (int q = 0; q < 8; q++) {
                hi[q] = __builtin_amdgcn_perm(pk[2 * q + 1], pk[2 * q], 0x05040100u);
                lo[q] = __builtin_amdgcn_perm(pk[2 * q + 1], pk[2 * q], 0x07060302u);
            }
            *(uint4*)&Ah[srow * TW + skoff]     = ((uint4*)hi)[0];
            *(uint4*)&Ah[srow * TW + skoff + 8] = ((uint4*)hi)[1];
            *(uint4*)&Al[srow * TW + skoff]     = ((uint4*)lo)[0];
            *(uint4*)&Al[srow * TW + skoff + 8] = ((uint4*)lo)[1];
        }
        __syncthreads();
        short8 afh[4], afl[4], bfh[4], bfl[4];
        #pragma unroll
        for (int i = 0; i < 4; i++) {
            const int ro = (wm * 64 + i * 16 + l15) * TW + lq * 8;
            afh[i] = *(const short8*)&Ah[ro];
            afl[i] = *(const short8*)&Al[ro];
        }
        #pragma unroll
        for (int j = 0; j < 4; j++) {
            const int ro = (wn * 64 + j * 16 + l15) * TW + lq * 8;
            bfh[j] = *(const short8*)&Bh[ro];
            bfl[j] = *(const short8*)&Bl[ro];
        }
        #pragma unroll
        for (int i = 0; i < 4; i++)
            #pragma unroll
            for (int j = 0; j < 4; j++) {
                acc[i][j] = __builtin_amdgcn_mfma_f32_16x16x32_bf16(afh[i], bfl[j], acc[i][j], 0, 0, 0);
                acc[i][j] = __builtin_amdgcn_mfma_f32_16x16x32_bf16(afl[i], bfh[j], acc[i][j], 0, 0, 0);
                acc[i][j] = __builtin_amdgcn_mfma_f32_16x16x32_bf16(afh[i], bfh[j], acc[i][j], 0, 0, 0);
            }
        __syncthreads();
    }
    if (d.flags & FL_MSGS) {
        #pragma unroll
        for (int i = 0; i < 4; i++) {
            #pragma unroll
            for (int r = 0; r < 4; r++) {
                const int row = bm + wm * 64 + i * 16 + lq * 4 + r;
                const int fi = d.fidx[row], ti = d.tidx[row];
                #pragma unroll
                for (int j = 0; j < 4; j++) {
                    const int col = bn + wn * 64 + j * 16 + l15;
                    float v = 2.f * (acc[i][j][r] + d.bias[col])
                            + d.qs[(size_t)fi * 256 + col] + d.qs[(size_t)ti * 256 + col];
                    ((u32*)d.C)[(size_t)row * d.ldc + col] = packhl(v);
                }
            }
        }
        return;
    }
    const int relu = d.flags & FL_RELU;
    const int opk  = d.flags & FL_OUTPK;
    #pragma unroll
    for (int j = 0; j < 4; j++) {
        const int col = bn + wn * 64 + j * 16 + l15;
        const bool cok = (col < d.Ncap);
        const float bv = (d.bias && cok) ? d.bias[col] : 0.f;
        #pragma unroll
        for (int i = 0; i < 4; i++) {
            const int row0 = bm + wm * 64 + i * 16 + lq * 4;
            #pragma unroll
            for (int r = 0; r < 4; r++) {
                float v = acc[i][j][r] + bv;
                if (relu) v = fmaxf(v, 0.f);
                if (cok) {
                    if (opk)
                        ((u32*)d.C)[(size_t)(row0 + r) * d.ldc + col] = packhl(v);
                    else
                        ((float*)d.C)[(size_t)(row0 + r) * d.ldc + col] = v;
                }
            }
        }
    }
}

static inline void gemm2(hipStream_t s, const GemmDesc& d0, const GemmDesc& d1)
{
    gemm2_pk_kernel<<<d0.nblk + d1.nblk, 256, 0, s>>>(d0, d1, d0.nblk);
}
static inline void gemm1(hipStream_t s, const GemmDesc& d0)
{
    gemm2_pk_kernel<<<d0.nblk, 256, 0, s>>>(d0, d0, d0.nblk);
}

// ---------------------------------------------------------------------------
// es1 GEMM with the msgs transform folded into A-staging (dedicated kernel,
// no runtime branch in the K-loop — round-1 lesson). BM=128, BN=64, K=256.
//   A_eff[row][c] = qs[f[row]][c] + qs[t[row]][c] + 2*unpackhl(ec2[row][c])
// Replaces the separate 24576-block msgs_inplace dispatch; the post-msgs
// A_ec2 was consumed ONLY by es1 (next k rewrites it), so no one misses it.
// ---------------------------------------------------------------------------
__global__ __launch_bounds__(256) void gemm_es1msgs_kernel(
    const u32* __restrict__ A,
    const float* __restrict__ qs,
    const int* __restrict__ fidx, const int* __restrict__ tidx,
    const u16* __restrict__ Wh, const u16* __restrict__ Wl,
    const float* __restrict__ bias,
    u32* __restrict__ C)
{
    __shared__ __align__(16) u16 Ah[128 * TW];
    __shared__ __align__(16) u16 Al[128 * TW];
    __shared__ __align__(16) u16 Bh[64 * TW];
    __shared__ __align__(16) u16 Bl[64 * TW];
    const int tid = threadIdx.x;
    const int lane = tid & 63, wave = tid >> 6;
    const int wm = wave >> 1, wn = wave & 1;
    const int bm = blockIdx.y * 128;
    const int AR = tid >> 1, AKo = (tid & 1) * 16;
    const int BR = tid >> 2, BKo = (tid & 3) * 8;
    const int arow = bm + AR;
    const int l15 = lane & 15, lq = lane >> 4;
    const int fi = fidx[arow], ti = tidx[arow];

    floatx4 acc[4][2];
    #pragma unroll
    for (int i = 0; i < 4; i++)
        #pragma unroll
        for (int j = 0; j < 2; j++) acc[i][j] = (floatx4){0.f, 0.f, 0.f, 0.f};

    for (int k0 = 0; k0 < 256; k0 += 32) {
        {
            const int kk = k0 + BKo;
            const u16* bh = Wh + (size_t)BR * 256 + kk;
            const u16* bl = Wl + (size_t)BR * 256 + kk;
            *(uint4*)&Bh[BR * TW + BKo] = ((const uint4*)bh)[0];
            *(uint4*)&Bl[BR * TW + BKo] = ((const uint4*)bl)[0];
        }
        {
            const int kk = k0 + AKo;
            const u32* asrc = A + (size_t)arow * 256 + kk;
            u32 pk[16];
            ((uint4*)pk)[0] = ((const uint4*)asrc)[0];
            ((uint4*)pk)[1] = ((const uint4*)asrc)[1];
            ((uint4*)pk)[2] = ((const uint4*)asrc)[2];
            ((uint4*)pk)[3] = ((const uint4*)asrc)[3];
            float qf[16], qt[16];
            const float* qfp = qs + (size_t)fi * 256 + kk;
            const float* qtp = qs + (size_t)ti * 256 + kk;
            #pragma unroll
            for (int q = 0; q < 4; q++) {
                ((float4*)qf)[q] = ((const float4*)qfp)[q];
                ((float4*)qt)[q] = ((const float4*)qtp)[q];
            }
            u16 ph[16], pl8[16];
            #pragma unroll
            for (int q = 0; q < 16; q++) {
                float v = qf[q] + qt[q] + 2.f * unpackhl(pk[q]);
                u16 h = f2bf(v);
                ph[q] = h;
                pl8[q] = f2bf(v - bf2f(h));
            }
            *(uint4*)&Ah[AR * TW + AKo]     = *(const uint4*)&ph[0];
            *(uint4*)&Ah[AR * TW + AKo + 8] = *(const uint4*)&ph[8];
            *(uint4*)&Al[AR * TW + AKo]     = *(const uint4*)&pl8[0];
            *(uint4*)&Al[AR * TW + AKo + 8] = *(const uint4*)&pl8[8];
        }
        __syncthreads();
        short8 afh[4], afl[4], bfh[2], bfl[2];
        #pragma unroll
        for (int i = 0; i < 4; i++) {
            const int ro = (wm * 64 + i * 16 + l15) * TW + lq * 8;
            afh[i] = *(const short8*)&Ah[ro];
            afl[i] = *(const short8*)&Al[ro];
        }
        #pragma unroll
        for (int j = 0; j < 2; j++) {
            const int ro = (wn * 32 + j * 16 + l15) * TW + lq * 8;
            bfh[j] = *(const short8*)&Bh[ro];
            bfl[j] = *(const short8*)&Bl[ro];
        }
        #pragma unroll
        for (int i = 0; i < 4; i++)
            #pragma unroll
            for (int j = 0; j < 2; j++) {
                acc[i][j] = __builtin_amdgcn_mfma_f32_16x16x32_bf16(afh[i], bfl[j], acc[i][j], 0, 0, 0);
                acc[i][j] = __builtin_amdgcn_mfma_f32_16x16x32_bf16(afl[i], bfh[j], acc[i][j], 0, 0, 0);
                acc[i][j] = __builtin_amdgcn_mfma_f32_16x16x32_bf16(afh[i], bfh[j], acc[i][j], 0, 0, 0);
            }
        __syncthreads();
    }
    #pragma unroll
    for (int j = 0; j < 2; j++) {
        const int col = wn * 32 + j * 16 + l15;
        const float bv = bias[col];
        #pragma unroll
        for (int i = 0; i < 4; i++) {
            const int row0 = bm + wm * 64 + i * 16 + lq * 4;
            #pragma unroll
            for (int r = 0; r < 4; r++) {
                float v = fmaxf(acc[i][j][r] + bv, 0.f);
                C[(size_t)(row0 + r) * 64 + col] = packhl(v);
            }
        }
    }
}

// ---------------------------------------------------------------------------
// fp32-A GEMM for the two encoder calls only (K=32), BM=BN=128, packed out.
// ---------------------------------------------------------------------------
__global__ __launch_bounds__(256) void gemm_f32_kernel(
    const float* __restrict__ A, int lda, int K,
    const u16* __restrict__ Wh, const u16* __restrict__ Wl, int ldwt,
    const float* __restrict__ bias, u32* __restrict__ C, int ldc, int Ncap)
{
    __shared__ __align__(16) u16 Ah[128 * TW];
    __shared__ __align__(16) u16 Al[128 * TW];
    __shared__ __align__(16) u16 Bh[128 * TW];
    __shared__ __align__(16) u16 Bl[128 * TW];
    const int tid = threadIdx.x;
    const int lane = tid & 63, wave = tid >> 6;
    const int wm = wave >> 1, wn = wave & 1;
    const int bm = blockIdx.y * 128, bn = blockIdx.x * 128;
    const int srow = tid >> 1;
    const int skoff = (tid & 1) * 16;
    const int arow = bm + srow, brow = bn + srow;
    const int l15 = lane & 15, lq = lane >> 4;

    floatx4 acc[4][4];
    #pragma unroll
    for (int i = 0; i < 4; i++)
        #pragma unroll
        for (int j = 0; j < 4; j++) acc[i][j] = (floatx4){0.f, 0.f, 0.f, 0.f};

    for (int k0 = 0; k0 < K; k0 += 32) {
        const int kk = k0 + skoff;
        const float* asrc = A + (size_t)arow * lda + kk;
        float f[16];
        ((float4*)f)[0] = ((const float4*)asrc)[0];
        ((float4*)f)[1] = ((const float4*)asrc)[1];
        ((float4*)f)[2] = ((const float4*)asrc)[2];
        ((float4*)f)[3] = ((const float4*)asrc)[3];
        u16 ph[16], pl8[16];
        #pragma unroll
        for (int q = 0; q < 16; q++) {
            u16 h = f2bf(f[q]);
            ph[q] = h;
            pl8[q] = f2bf(f[q] - bf2f(h));
        }
        *(uint4*)&Ah[srow * TW + skoff]     = *(const uint4*)&ph[0];
        *(uint4*)&Ah[srow * TW + skoff + 8] = *(const uint4*)&ph[8];
        *(uint4*)&Al[srow * TW + skoff]     = *(const uint4*)&pl8[0];
        *(uint4*)&Al[srow * TW + skoff + 8] = *(const uint4*)&pl8[8];
        const u16* bh = Wh + (size_t)brow * ldwt + kk;
        const u16* bl = Wl + (size_t)brow * ldwt + kk;
        *(uint4*)&Bh[srow * TW + skoff]     = ((const uint4*)bh)[0];
        *(uint4*)&Bh[srow * TW + skoff + 8] = ((const uint4*)bh)[1];
        *(uint4*)&Bl[srow * TW + skoff]     = ((const uint4*)bl)[0];
        *(uint4*)&Bl[srow * TW + skoff + 8] = ((const uint4*)bl)[1];
        __syncthreads();
        short8 afh[4], afl[4], bfh[4], bfl[4];
        #pragma unroll
        for (int i = 0; i < 4; i++) {
            const int ro = (wm * 64 + i * 16 + l15) * TW + lq * 8;
            afh[i] = *(const short8*)&Ah[ro];
            afl[i] = *(const short8*)&Al[ro];
        }
        #pragma unroll
        for (int j = 0; j < 4; j++) {
            const int ro = (wn * 64 + j * 16 + l15) * TW + lq * 8;
            bfh[j] = *(const short8*)&Bh[ro];
            bfl[j] = *(const short8*)&Bl[ro];
        }
        #pragma unroll
        for (int i = 0; i < 4; i++)
            #pragma unroll
            for (int j = 0; j < 4; j++) {
                acc[i][j] = __builtin_amdgcn_mfma_f32_16x16x32_bf16(afh[i], bfl[j], acc[i][j], 0, 0, 0);
                acc[i][j] = __builtin_amdgcn_mfma_f32_16x16x32_bf16(afl[i], bfh[j], acc[i][j], 0, 0, 0);
                acc[i][j] = __builtin_amdgcn_mfma_f32_16x16x32_bf16(afh[i], bfh[j], acc[i][j], 0, 0, 0);
            }
        __syncthreads();
    }
    #pragma unroll
    for (int j = 0; j < 4; j++) {
        const int col = bn + wn * 64 + j * 16 + l15;
        const bool cok = (col < Ncap);
        const float bv = cok ? bias[col] : 0.f;
        #pragma unroll
        for (int i = 0; i < 4; i++) {
            const int row0 = bm + wm * 64 + i * 16 + lq * 4;
            #pragma unroll
            for (int r = 0; r < 4; r++) {
                if (cok)
                    C[(size_t)(row0 + r) * ldc + col] = packhl(acc[i][j][r] + bv);
            }
        }
    }
}

// ---------------------------------------------------------------------------
// One-shot weight prep (all transposed hi/lo bf16 planes; Wsum inline).
// ---------------------------------------------------------------------------
__global__ __launch_bounds__(256) void prep_kernel(
    const float* __restrict__ niW1, const float* __restrict__ niW2,
    const float* __restrict__ eiW1, const float* __restrict__ eiW2,
    const float* __restrict__ msgW, const float* __restrict__ nuW1,
    const float* __restrict__ nuW2, const float* __restrict__ encnW,
    const float* __restrict__ enceW, const float* __restrict__ nsW1,
    const float* __restrict__ nsW2, const float* __restrict__ esW1,
    const float* __restrict__ esW2,
    u16* __restrict__ WT, u16* __restrict__ WTL)
{
    int idx = blockIdx.x * 256 + threadIdx.x;
    if (idx >= 696320) return;
    const float* src; int base, N, Npad, ldk, noff = 0, wtoff;
    int wsum = 0;
    if      (idx < 65536)  { src = niW1;  base = 0;      N = 256; Npad = 256; ldk = 256; wtoff = 0; }
    else if (idx < 98304)  { src = niW2;  base = 65536;  N = 128; Npad = 128; ldk = 256; wtoff = 65536; }
    else if (idx < 245760) { src = eiW1;  base = 98304;  N = 384; Npad = 384; ldk = 384; wtoff = 98304; }
    else if (idx < 294912) { src = eiW2;  base = 245760; N = 128; Npad = 128; ldk = 384; wtoff = 245760; }
    else if (idx < 393216) { src = msgW;  base = 294912; N = 256; Npad = 256; ldk = 384; wtoff = 294912; }
    else if (idx < 425984) { src = msgW;  base = 393216; N = 256; Npad = 256; ldk = 128; wtoff = 393216; }
    else if (idx < 458752) { src = msgW + 32768; base = 425984; N = 256; Npad = 256; ldk = 128; noff = 256; wtoff = 393216; }
    else if (idx < 557056) { src = nuW1;  base = 458752; N = 256; Npad = 256; ldk = 384; wtoff = 458752; }
    else if (idx < 589824) { src = nuW2;  base = 557056; N = 128; Npad = 128; ldk = 256; wtoff = 557056; }
    else if (idx < 622592) { src = msgW;  base = 589824; N = 256; Npad = 256; ldk = 128; wtoff = 589824; wsum = 1; }
    else if (idx < 626688) { src = encnW; base = 622592; N = 128; Npad = 128; ldk = 32;  wtoff = 622592; }
    else if (idx < 630784) { src = enceW; base = 626688; N = 128; Npad = 128; ldk = 32;  wtoff = 626688; }
    else if (idx < 647168) { src = nsW1;  base = 630784; N = 64;  Npad = 128; ldk = 128; wtoff = 630784; }
    else if (idx < 655360) { src = nsW2;  base = 647168; N = 64;  Npad = 128; ldk = 64;  wtoff = 647168; }
    else if (idx < 688128) { src = esW1;  base = 655360; N = 64;  Npad = 128; ldk = 256; wtoff = 655360; }
    else                   { src = esW2;  base = 688128; N = 64;  Npad = 128; ldk = 64;  wtoff = 688128; }
    int rel = idx - base;
    int k = rel / Npad, n = rel % Npad;
    float v = 0.f;
    if (n < N) {
        v = src[(size_t)k * N + n];
        if (wsum) v += src[32768 + (size_t)k * N + n];
    }
    u16 h = f2bf(v);
    size_t o = (size_t)wtoff + (size_t)(noff + n) * ldk + k;
    WT[o] = h;
    WTL[o] = f2bf(v - bf2f(h));
}

// ---------------------------------------------------------------------------
// Dual batched MFMA plan-GEMM: qi (transp=0) + ci (transp=1) in one launch.
// P PACKED-hl; U packed-hl; C packed-hl.
// ---------------------------------------------------------------------------
__global__ __launch_bounds__(256) void bgemm_dual_kernel(
    const u32* __restrict__ P, int ms, int n_per,
    const u32* __restrict__ U, int ldu,
    u32* __restrict__ C, int ldc, int nxh)
{
    __shared__ __align__(16) u16 Ah[64 * TW];
    __shared__ __align__(16) u16 Al[64 * TW];
    __shared__ __align__(16) u16 Bh[128 * TW];
    __shared__ __align__(16) u16 Bl[128 * TW];
    const int b = blockIdx.z;
    const u32* Pb = P + (size_t)b * ms * ms;
    const int bxr = blockIdx.x;
    const int transp = (bxr >= nxh) ? 1 : 0;
    const int bn = (bxr - transp * nxh) * 128;
    const int qbase = (2 * b) * n_per, cbase = (2 * b + 1) * n_per;
    const int obase = transp ? cbase : qbase;
    const int ibase = transp ? qbase : cbase;
    const int bm = blockIdx.y * 64;
    const int tid = threadIdx.x, lane = tid & 63, wave = tid >> 6;
    const int wm = wave >> 1, wn = wave & 1;
    const int l15 = lane & 15, lq = lane >> 4;
    const int sar = tid >> 2, sak = (tid & 3) * 8;
    const int sbn = tid >> 1, sbk = (tid & 1) * 16;
    const int Kpad = (n_per + 31) & ~31;

    floatx4 acc[2][4];
    #pragma unroll
    for (int i = 0; i < 2; i++)
        #pragma unroll
        for (int j = 0; j < 4; j++) acc[i][j] = (floatx4){0.f, 0.f, 0.f, 0.f};

    for (int k0 = 0; k0 < Kpad; k0 += 32) {
        {
            const int m = bm + sar;
            u32 pk[8];
            if (m < n_per) {
                if (!transp) {
                    const u32* src = Pb + (size_t)m * ms + k0 + sak;
                    ((uint4*)pk)[0] = ((const uint4*)src)[0];
                    ((uint4*)pk)[1] = ((const uint4*)src)[1];
                } else {
                    #pragma unroll
                    for (int i = 0; i < 8; i++)
                        pk[i] = Pb[(size_t)(k0 + sak + i) * ms + m];
                }
                #pragma unroll
                for (int i = 0; i < 8; i++)
                    if (k0 + sak + i >= n_per) pk[i] = 0;
            } else {
                #pragma unroll
                for (int i = 0; i < 8; i++) pk[i] = 0;
            }
            u32 hi[4], lo[4];
            #pragma unroll
            for (int q = 0; q < 4; q++) {
                hi[q] = __builtin_amdgcn_perm(pk[2 * q + 1], pk[2 * q], 0x05040100u);
                lo[q] = __builtin_amdgcn_perm(pk[2 * q + 1], pk[2 * q], 0x07060302u);
            }
            *(uint4*)&Ah[sar * TW + sak] = *(uint4*)hi;
            *(uint4*)&Al[sar * TW + sak] = *(uint4*)lo;
        }
        {
            u16 qh[16], ql[16];
            #pragma unroll
            for (int i = 0; i < 16; i++) {
                int kk = k0 + sbk + i;
                u32 w = 0;
                if (kk < n_per) w = U[(size_t)(ibase + kk) * ldu + bn + sbn];
                qh[i] = (u16)w; ql[i] = (u16)(w >> 16);
            }
            *(uint4*)&Bh[sbn * TW + sbk]     = *(const uint4*)&qh[0];
            *(uint4*)&Bh[sbn * TW + sbk + 8] = *(const uint4*)&qh[8];
            *(uint4*)&Bl[sbn * TW + sbk]     = *(const uint4*)&ql[0];
            *(uint4*)&Bl[sbn * TW + sbk + 8] = *(const uint4*)&ql[8];
        }
        __syncthreads();
        short8 afh[2], afl[2], bfh[4], bfl[4];
        #pragma unroll
        for (int i = 0; i < 2; i++) {
            const int ro = (wm * 32 + i * 16 + l15) * TW + lq * 8;
            afh[i] = *(const short8*)&Ah[ro];
            afl[i] = *(const short8*)&Al[ro];
        }
        #pragma unroll
        for (int j = 0; j < 4; j++) {
            const int ro = (wn * 64 + j * 16 + l15) * TW + lq * 8;
            bfh[j] = *(const short8*)&Bh[ro];
            bfl[j] = *(const short8*)&Bl[ro];
        }
        #pragma unroll
        for (int i = 0; i < 2; i++)
            #pragma unroll
            for (int j = 0; j < 4; j++) {
                acc[i][j] = __builtin_amdgcn_mfma_f32_16x16x32_bf16(afh[i], bfl[j], acc[i][j], 0, 0, 0);
                acc[i][j] = __builtin_amdgcn_mfma_f32_16x16x32_bf16(afl[i], bfh[j], acc[i][j], 0, 0, 0);
                acc[i][j] = __builtin_amdgcn_mfma_f32_16x16x32_bf16(afh[i], bfh[j], acc[i][j], 0, 0, 0);
            }
        __syncthreads();
    }
    #pragma unroll
    for (int j = 0; j < 4; j++) {
        const int col = bn + wn * 64 + j * 16 + l15;
        #pragma unroll
        for (int i = 0; i < 2; i++) {
            const int row0 = bm + wm * 32 + i * 16 + lq * 4;
            #pragma unroll
            for (int r = 0; r < 4; r++) {
                const int m = row0 + r;
                if (m < n_per)
                    C[(size_t)(obase + m) * ldc + col] = packhl(acc[i][j][r]);
            }
        }
    }
}

static inline void bgemmDual(hipStream_t s, const u32* P, int ms, int n_per,
                             const u32* U, int ldu, u32* C, int ldc, int N)
{
    int nxh = N / 128;
    dim3 grid(nxh * 2, (n_per + 63) / 64, Bb);
    bgemm_dual_kernel<<<grid, 256, 0, s>>>(P, ms, n_per, U, ldu, C, ldc, nxh);
}

// ---------------------------------------------------------------------------
// Merged la dispatch: blocks 0..63 = node la+sinkhorn64 (packed plan out);
// blocks 64..1087 = edge la 256x256 tiles. Overlaps the low-fill sinkhorn64
// with the 1024-block edge la. k=2 launches only 64 blocks (node part).
// ---------------------------------------------------------------------------
__global__ __launch_bounds__(256) void la_fused_kernel(
    const float* __restrict__ ttn, u32* __restrict__ n_la,
    const float* __restrict__ tte, float* __restrict__ ela)
{
    __shared__ float Aq[64][65];
    __shared__ float Ac[64][65];
    __shared__ float m[64][65];
    __shared__ float v_s[64];
    __shared__ float part[4][64];
    const int tid = threadIdx.x;
    if ((int)blockIdx.x >= 64) {
        // ---- edge la tile ----
        const int id = blockIdx.x - 64;
        const int b = id >> 4;
        const int bm = ((id >> 2) & 3) * 64, bn = (id & 3) * 64;
        for (int idx = tid; idx < 4096; idx += 256) {
            int r = idx >> 6, s = idx & 63;
            float vq = 0.f, vc = 0.f;
            int qr = bm + r, cr = bn + r;
            if (qr < Ee) vq = tte[((size_t)(2 * b) * Ee + qr) * Sdim + s];
            if (cr < Ee) vc = tte[((size_t)(2 * b + 1) * Ee + cr) * Sdim + s];
            Aq[r][s] = vq;
            Ac[r][s] = vc;
        }
        __syncthreads();
        const int tx = tid & 15, ty = tid >> 4;
        float acc[4][4] = {};
        for (int s = 0; s < 64; s++) {
            float a[4], c[4];
            #pragma unroll
            for (int i = 0; i < 4; i++) a[i] = Aq[ty * 4 + i][s];
            #pragma unroll
            for (int j = 0; j < 4; j++) c[j] = Ac[tx * 4 + j][s];
            #pragma unroll
            for (int i = 0; i < 4; i++)
                #pragma unroll
                for (int j = 0; j < 4; j++)
                    acc[i][j] = fmaf(a[i], c[j], acc[i][j]);
        }
        #pragma unroll
        for (int i = 0; i < 4; i++)
            #pragma unroll
            for (int j = 0; j < 4; j++)
                ela[((size_t)b * 256 + bm + ty * 4 + i) * 256 + bn + tx * 4 + j] = acc[i][j] * INV_TEMP;
        return;
    }
    // ---- node la + sinkhorn64 ----
    const int b = blockIdx.x;
    const int lane = tid & 63, w = tid >> 6;
    for (int idx = tid; idx < 4096; idx += 256) {
        int r = idx >> 6, s = idx & 63;
        float vq = 0.f, vc = 0.f;
        if (r < Nn) {
            vq = ttn[((size_t)(2 * b) * Nn + r) * Sdim + s];
            vc = ttn[((size_t)(2 * b + 1) * Nn + r) * Sdim + s];
        }
        Aq[r][s] = vq;
        Ac[r][s] = vc;
    }
    __syncthreads();
    {
        const int tx = tid & 15, ty = tid >> 4;
        float acc[4][4] = {};
        for (int s = 0; s < 64; s++) {
            float a[4], c[4];
            #pragma unroll
            for (int i = 0; i < 4; i++) a[i] = Aq[ty * 4 + i][s];
            #pragma unroll
            for (int j = 0; j < 4; j++) c[j] = Ac[tx * 4 + j][s];
            #pragma unroll
            for (int i = 0; i < 4; i++)
                #pragma unroll
                for (int j = 0; j < 4; j++)
                    acc[i][j] = fmaf(a[i], c[j], acc[i][j]);
        }
        #pragma unroll
        for (int i = 0; i < 4; i++)
            #pragma unroll
            for (int j = 0; j < 4; j++)
                m[ty * 4 + i][tx * 4 + j] = acc[i][j] * INV_TEMP;
    }
    if (tid < 64) v_s[tid] = 0.f;
    __syncthreads();
    float x[16], u[16];
    #pragma unroll
    for (int j = 0; j < 16; j++) x[j] = m[w * 16 + j][lane];
    #pragma unroll
    for (int j = 0; j < 16; j++) {
        float mx = x[j];
        #pragma unroll
        for (int d = 1; d < 64; d <<= 1) mx = fmaxf(mx, __shfl_xor(mx, d));
        u[j] = mx;
    }
    for (int it = 0; it < 10; it++) {
        float vr = v_s[lane];
        #pragma unroll
        for (int j = 0; j < 16; j++) {
            float s = __expf(x[j] - vr - u[j]);
            #pragma unroll
            for (int d = 1; d < 64; d <<= 1) s += __shfl_xor(s, d);
            u[j] += __logf(s);
        }
        float s = 0.f;
        #pragma unroll
        for (int j = 0; j < 16; j++) s += __expf(x[j] - u[j] - vr);
        part[w][lane] = s;
        __syncthreads();
        if (tid < 64) {
            float ss = part[0][tid] + part[1][tid] + part[2][tid] + part[3][tid];
            v_s[tid] += __logf(ss);
        }
        __syncthreads();
    }
    float vr = v_s[lane];
    u32* g = n_la + (size_t)b * 4096;
    #pragma unroll
    for (int j = 0; j < 16; j++)
        g[(size_t)(w * 16 + j) * 64 + lane] = packhl(__expf(x[j] - u[j] - vr));
}

// ---------------------------------------------------------------------------
// Sinkhorn 256x256, single-pass streaming form (measured 91 us; the reg-
// cached variant spilled at the 64-VGPR cap and ran 96 us). Packed epilogue.
// ---------------------------------------------------------------------------
__global__ __launch_bounds__(1024) void sinkhorn256_kernel(float* __restrict__ la)
{
    const int b = blockIdx.x;
    float* g = la + (size_t)b * 65536;
    const int tid = threadIdx.x;
    const int lane = tid & 63, w = tid >> 6;
    __shared__ float v_s[256];
    __shared__ float part[16][64][5];  // [wave][lane][q], stride-5 pad

    float u[16];
    #pragma unroll
    for (int j = 0; j < 16; j++) {
        float4 xv = ((const float4*)(g + (size_t)(w * 16 + j) * 256))[lane];
        float mx = fmaxf(fmaxf(xv.x, xv.y), fmaxf(xv.z, xv.w));
        #pragma unroll
        for (int d = 1; d < 64; d <<= 1) mx = fmaxf(mx, __shfl_xor(mx, d));
        u[j] = mx;
    }
    if (tid < 256) v_s[tid] = 0.f;
    __syncthreads();

    for (int it = 0; it < 10; it++) {
        const float4 vr = *(const float4*)&v_s[4 * lane];
        float cp0 = 0.f, cp1 = 0.f, cp2 = 0.f, cp3 = 0.f;
        #pragma unroll
        for (int j = 0; j < 16; j++) {
            float4 xv = ((const float4*)(g + (size_t)(w * 16 + j) * 256))[lane];
            float e0 = __expf(xv.x - vr.x - u[j]);
            float e1 = __expf(xv.y - vr.y - u[j]);
            float e2 = __expf(xv.z - vr.z - u[j]);
            float e3 = __expf(xv.w - vr.w - u[j]);
            float s = e0 + e1 + e2 + e3;
            #pragma unroll
            for (int d = 1; d < 64; d <<= 1) s += __shfl_xor(s, d);
            u[j] += __logf(s);
            const float inv = 1.f / s;
            cp0 = fmaf(e0, inv, cp0);
            cp1 = fmaf(e1, inv, cp1);
            cp2 = fmaf(e2, inv, cp2);
            cp3 = fmaf(e3, inv, cp3);
        }
        *(float4*)&part[w][lane][0] = (float4){cp0, cp1, cp2, cp3};
        __syncthreads();
        if (tid < 256) {
            const int cl = tid >> 2, cq = tid & 3;
            float ss = 0.f;
            #pragma unroll
            for (int w2 = 0; w2 < 16; w2++) ss += part[w2][cl][cq];
            v_s[tid] += __logf(ss);
        }
        __syncthreads();
    }
    const float4 vr = *(const float4*)&v_s[4 * lane];
    #pragma unroll
    for (int j = 0; j < 16; j++) {
        float4* rp = (float4*)(g + (size_t)(w * 16 + j) * 256) + lane;
        float4 xv = *rp;
        u32 o[4];
        o[0] = packhl(__expf(xv.x - u[j] - vr.x));
        o[1] = packhl(__expf(xv.y - u[j] - vr.y));
        o[2] = packhl(__expf(xv.z - u[j] - vr.z));
        o[3] = packhl(__expf(xv.w - u[j] - vr.w));
        *(uint4*)rp = *(uint4*)o;
    }
}

// ---------------------------------------------------------------------------
// CSR adjacency (built once; graph fixed for the whole launch).
// ---------------------------------------------------------------------------
__global__ __launch_bounds__(256) void zero_deg_kernel(int* __restrict__ deg)
{
    deg[blockIdx.x * 256 + threadIdx.x] = 0;
}

__global__ __launch_bounds__(256) void csr_build_kernel(
    const int* __restrict__ from_idx, const int* __restrict__ to_idx,
    int* __restrict__ deg, u32* __restrict__ adj)
{
    int e = blockIdx.x * 256 + threadIdx.x;
    if (e >= VEe) return;
    int f = from_idx[e], t = to_idx[e];
    int p1 = atomicAdd(&deg[t], 1);
    if (p1 < ADJ_STRIDE) adj[(size_t)t * ADJ_STRIDE + p1] = ((u32)e << 13) | (u32)f;
    int p2 = atomicAdd(&deg[f], 1);
    if (p2 < ADJ_STRIDE) adj[(size_t)f * ADJ_STRIDE + p2] = ((u32)e << 13) | (u32)t;
}

__global__ __launch_bounds__(256) void agg_csr_kernel(
    const u32* __restrict__ P01,
    const u32* __restrict__ ec2,
    const int* __restrict__ deg, const u32* __restrict__ adj,
    u32* __restrict__ agg)
{
    const int n = blockIdx.x;
    const int d = threadIdx.x;
    __shared__ u32 sadj[ADJ_STRIDE];
    __shared__ int sdeg;
    if (d == 0) sdeg = min(deg[n], ADJ_STRIDE);
    if (d < ADJ_STRIDE) sadj[d] = adj[(size_t)n * ADJ_STRIDE + d];
    __syncthreads();
    const int dn = sdeg;
    float a = (float)dn * unpackhl(P01[(size_t)n * 512 + 256 + d]);
    for (int i = 0; i < dn; i++) {
        const u32 en = sadj[i];
        const int e = (int)(en >> 13), pr = (int)(en & 8191u);
        a += unpackhl(ec2[(size_t)e * 256 + d]) + unpackhl(P01[(size_t)pr * 512 + d]);
    }
    agg[(size_t)n * 256 + d] = packhl(a);
}

__global__ void diag_kernel(float* __restrict__ out, float v)
{
    out[threadIdx.x] = v;
}

// score[b] = -sum relu( ffq - plan@ffc ); upd_node + plan packed-hl.
__global__ __launch_bounds__(128) void score_kernel(
    const u32* __restrict__ upd_node, const u32* __restrict__ plan,
    float* __restrict__ out)
{
    const int b = blockIdx.x;
    const int tid = threadIdx.x;
    __shared__ float ffc[48][128];
    __shared__ float pl[64][48];
    __shared__ float red[128];
    for (int c = 0; c < 48; c++)
        ffc[c][tid] = unpackhl(upd_node[(size_t)((2 * b + 1) * 48 + c) * 640 + 512 + tid]);
    for (int idx = tid; idx < 64 * 48; idx += 128) {
        int q = idx / 48, c = idx % 48;
        pl[q][c] = unpackhl(plan[(size_t)b * 4096 + q * 64 + c]);
    }
    __syncthreads();
    float accv = 0.f;
    for (int q = 0; q < 64; q++) {
        float rsum = 0.f;
        #pragma unroll 8
        for (int c = 0; c < 48; c++) rsum = fmaf(pl[q][c], ffc[c][tid], rsum);
        float fq = 0.f;
        if (q < 48) fq = unpackhl(upd_node[(size_t)((2 * b) * 48 + q) * 640 + 512 + tid]);
        accv += fmaxf(fq - rsum, 0.f);
    }
    red[tid] = accv;
    __syncthreads();
    for (int sft = 64; sft > 0; sft >>= 1) {
        if (tid < sft) red[tid] += red[tid + sft];
        __syncthreads();
    }
    if (tid == 0) out[b] = -red[0];
}

// ---------------------------------------------------------------------------
// Workspace layout (floats). Total 66,861,056 floats = 267.44 MB.
// ---------------------------------------------------------------------------
#define OFF_UPD_NODE   0ULL
#define OFF_NODE_STORE 3932160ULL
#define OFF_EDGE_STORE 7077888ULL
#define OFF_ECOMB      32243712ULL
#define OFF_ENC_N      47972352ULL
#define OFF_ENC_E      48758784ULL
#define OFF_N_LA       51904512ULL
#define OFF_WT         52199424ULL
#define OFF_WTL        52547584ULL
#define OFF_ARENA      52895744ULL
#define OFF_DEG        66265088ULL
#define OFF_ADJ        66271232ULL
#define TOTAL_FLOATS   66861056ULL

// bf16 weight sub-offsets (u16 from WT/WTL base)
#define WT_NIW1   0
#define WT_NIW2   65536
#define WT_EIW1   98304
#define WT_EIW2   245760
#define WT_MSG    294912
#define WT_P01    393216
#define WT_NUW1   458752
#define WT_NUW2   557056
#define WT_WSUM   589824
#define WT_ENCN   622592
#define WT_ENCE   626688
#define WT_NS1    630784
#define WT_NS2    647168
#define WT_ES1    655360
#define WT_ES2    688128

#define PK(p) ((u32*)(p))

extern "C" void kernel_launch(void* const* d_in, const int* in_sizes, int n_in,
                              void* d_out, int out_size, void* d_ws, size_t ws_size,
                              hipStream_t stream)
{
    (void)in_sizes; (void)n_in; (void)out_size;
    if (ws_size < TOTAL_FLOATS * sizeof(float)) {
        diag_kernel<<<1, 64, 0, stream>>>((float*)d_out, (float)ws_size);
        return;
    }

    const float* node_features = (const float*)d_in[0];
    const float* edge_features = (const float*)d_in[1];
    const int*   from_idx      = (const int*)d_in[2];
    const int*   to_idx        = (const int*)d_in[3];
    const float* enc_node_W = (const float*)d_in[4];
    const float* enc_node_b = (const float*)d_in[5];
    const float* enc_edge_W = (const float*)d_in[6];
    const float* enc_edge_b = (const float*)d_in[7];
    const float* ni_W1 = (const float*)d_in[8];
    const float* ni_b1 = (const float*)d_in[9];
    const float* ni_W2 = (const float*)d_in[10];
    const float* ni_b2 = (const float*)d_in[11];
    const float* ei_W1 = (const float*)d_in[12];
    const float* ei_b1 = (const float*)d_in[13];
    const float* ei_W2 = (const float*)d_in[14];
    const float* ei_b2 = (const float*)d_in[15];
    const float* msg_W = (const float*)d_in[16];
    const float* msg_b = (const float*)d_in[17];
    const float* nu_W1 = (const float*)d_in[18];
    const float* nu_b1 = (const float*)d_in[19];
    const float* nu_W2 = (const float*)d_in[20];
    const float* nu_b2 = (const float*)d_in[21];
    const float* ns_W1 = (const float*)d_in[22];
    const float* ns_b1 = (const float*)d_in[23];
    const float* ns_W2 = (const float*)d_in[24];
    const float* ns_b2 = (const float*)d_in[25];
    const float* es_W1 = (const float*)d_in[26];
    const float* es_b1 = (const float*)d_in[27];
    const float* es_W2 = (const float*)d_in[28];
    const float* es_b2 = (const float*)d_in[29];

    float* ws = (float*)d_ws;
    float* upd_node   = ws + OFF_UPD_NODE;
    float* node_store = ws + OFF_NODE_STORE;
    float* edge_store = ws + OFF_EDGE_STORE;
    float* ecomb      = ws + OFF_ECOMB;
    float* enc_n      = ws + OFF_ENC_N;
    float* enc_e      = ws + OFF_ENC_E;
    float* n_la       = ws + OFF_N_LA;
    u16* WT  = (u16*)(ws + OFF_WT);
    u16* WTL = (u16*)(ws + OFF_WTL);
    float* arena      = ws + OFF_ARENA;
    int* deg = (int*)(ws + OFF_DEG);
    u32* adj = (u32*)(ws + OFF_ADJ);

    // Phase-A arena carve
    float* A_hidden = arena;                  // VN x 256
    float* A_hcomb  = arena + 1572864;        // VN x 128
    float* A_ehid   = arena + 2359296;        // VE x 384
    float* A_ec2    = arena + 2359296;        // VE x 256 (alias)
    float* A_P01    = arena + 8650752;        // VN x 512
    float* A_aggb   = arena + 11796480;       // VN x 256
    // Phase-B carve
    float* B_Qs       = arena;                // VN x 256 (fp32) -- ping
    float* B_Qs2      = ecomb + (size_t)4 * VEe * 128; // pong (ecomb slot 4: free in phase-B)
    float* B_thid_e   = arena + 8650752;      // VE x 64
    float* B_ttreal_e = arena + 10223616;     // VE x 64 (fp32)
    float* B_ela      = arena + 2359296;      // 64 x 256 x 256 (fp32 -> packed in place)
    float* B_msgs     = arena + 6553600;      // VE x 256
    float* B_thid_n   = arena + 12058624;     // VN x 64
    float* B_ttreal_n = arena + 12451840;     // VN x 64 (fp32)

    // --- one-shot weight prep + CSR adjacency ---
    prep_kernel<<<(696320 + 255) / 256, 256, 0, stream>>>(
        ni_W1, ni_W2, ei_W1, ei_W2, msg_W, nu_W1, nu_W2,
        enc_node_W, enc_edge_W, ns_W1, ns_W2, es_W1, es_W2, WT, WTL);
    zero_deg_kernel<<<VNn / 256, 256, 0, stream>>>(deg);
    csr_build_kernel<<<VEe / 256, 256, 0, stream>>>(from_idx, to_idx, deg, adj);

    // --- encoders (fp32 A, packed out) ---
    gemm_f32_kernel<<<dim3(1, VNn / 128), 256, 0, stream>>>(
        node_features, 32, 32, WT + WT_ENCN, WTL + WT_ENCN, 32, enc_node_b, PK(enc_n), 128, 128);
    gemm_f32_kernel<<<dim3(1, VEe / 128), 256, 0, stream>>>(
        edge_features, 32, 32, WT + WT_ENCE, WTL + WT_ENCE, 32, enc_edge_b, PK(enc_e), 128, 128);

    for (int k = 0; k < 3; k++) {
        for (int p = 1; p <= 5; p++) {
            const bool hs = (k > 0) && (p > 1);
            const u32* hA1 = (p == 1) ? PK(enc_n) : PK(upd_node + (size_t)(p - 2) * 128);
            const int  hlda1 = (p == 1) ? 128 : 640;
            const u32* hA2 = hs ? PK(node_store + (size_t)(p - 2) * 128) : nullptr;
            const int  hK2 = hs ? 128 : 0;
            GemmDesc hcomb1_d = mkDesc(hA1, hlda1, 128, hA2, 512, hK2,
                                       WT + WT_NIW1, WTL + WT_NIW1, 256, ni_b1,
                                       A_hidden, 256, VNn, 256, 256, FL_RELU | FL_OUTPK);
            GemmDesc hcomb2_d = mkDesc(PK(A_hidden), 256, 256, nullptr, 0, 0,
                                       WT + WT_NIW2, WTL + WT_NIW2, 256, ni_b2,
                                       A_hcomb, 128, VNn, 128, 128, FL_OUTPK);
            GemmDesc p01_d = mkDesc(PK(A_hcomb), 128, 128, nullptr, 0, 0,
                                    WT + WT_P01, WTL + WT_P01, 128, nullptr,
                                    A_P01, 512, VNn, 512, 512, FL_OUTPK);

            const bool edge_full = ((k == 0 && p == 1) || (k > 0 && p > 1));
            if (edge_full) {
                const u32* esrc = (k == 0) ? nullptr : PK(edge_store + (size_t)(p - 2) * 256);
                const int  eK2  = (k == 0) ? 0 : 256;
                float* ec_slot = (k == 0) ? ecomb : ecomb + (size_t)(p - 1) * VEe * 128;
                GemmDesc eiW1_d = mkDesc(PK(enc_e), 128, 128, esrc, 1024, eK2,
                                         WT + WT_EIW1, WTL + WT_EIW1, 384, ei_b1,
                                         A_ehid, 384, VEe, 384, 384, FL_RELU | FL_OUTPK);
                GemmDesc eiW2_d = mkDesc(PK(A_ehid), 384, 384, nullptr, 0, 0,
                                         WT + WT_EIW2, WTL + WT_EIW2, 384, ei_b2,
                                         ec_slot, 128, VEe, 128, 128, FL_OUTPK);
                GemmDesc ec2_d = mkDesc(PK(ec_slot), 128, 128, nullptr, 0, 0,
                                        WT + WT_MSG + 256, WTL + WT_MSG + 256, 384, msg_b,
                                        A_ec2, 256, VEe, 256, 256, FL_OUTPK);
                gemm2(stream, eiW1_d, hcomb1_d);
                gemm2(stream, eiW2_d, hcomb2_d);
                gemm2(stream, ec2_d, p01_d);
            } else if (k > 0 && p == 1) {
                GemmDesc ec2_d = mkDesc(PK(ecomb), 128, 128, nullptr, 0, 0,
                                        WT + WT_MSG + 256, WTL + WT_MSG + 256, 384, msg_b,
                                        A_ec2, 256, VEe, 256, 256, FL_OUTPK);
                gemm2(stream, ec2_d, hcomb1_d);
                gemmPK(stream, 64, 64, PK(A_hidden), 256, 256, nullptr, 0, 0,
                       WT + WT_NIW2, WTL + WT_NIW2, 256,
                       ni_b2, A_hcomb, 128, VNn, 128, 128, FL_OUTPK);
                gemmPK(stream, 64, 128, PK(A_hcomb), 128, 128, nullptr, 0, 0,
                       WT + WT_P01, WTL + WT_P01, 128,
                       nullptr, A_P01, 512, VNn, 512, 512, FL_OUTPK);
            } else {
                gemmPK(stream, 64, 64, hA1, hlda1, 128, hA2, 512, hK2,
                       WT + WT_NIW1, WTL + WT_NIW1, 256, ni_b1,
                       A_hidden, 256, VNn, 256, 256, FL_RELU | FL_OUTPK);
                gemmPK(stream, 64, 64, PK(A_hidden), 256, 256, nullptr, 0, 0,
                       WT + WT_NIW2, WTL + WT_NIW2, 256,
                       ni_b2, A_hcomb, 128, VNn, 128, 128, FL_OUTPK);
                gemmPK(stream, 64, 128, PK(A_hcomb), 128, 128, nullptr, 0, 0,
                       WT + WT_P01, WTL + WT_P01, 128,
                       nullptr, A_P01, 512, VNn, 512, 512, FL_OUTPK);
            }
            agg_csr_kernel<<<VNn, 256, 0, stream>>>(PK(A_P01), PK(A_ec2), deg, adj, PK(A_aggb));
            gemmPK(stream, 64, 64, PK(A_hcomb), 128, 128, PK(A_aggb), 256, 256,
                   WT + WT_NUW1, WTL + WT_NUW1, 384,
                   nu_b1, A_hidden, 256, VNn, 256, 256, FL_RELU | FL_OUTPK);
            gemmPK(stream, 64, 64, PK(A_hidden), 256, 256, nullptr, 0, 0,
                   WT + WT_NUW2, WTL + WT_NUW2, 256,
                   nu_b2, upd_node + (size_t)(p - 1) * 128, 640, VNn, 128, 128, FL_OUTPK);
        }
        if (k < 2) {
            // ---- Qs (slot 5) || ns1 ----
            GemmDesc qs_d = mkDesc(PK(upd_node + 512), 640, 128, nullptr, 0, 0,
                                   WT + WT_WSUM, WTL + WT_WSUM, 128, nullptr,
                                   B_Qs, 256, VNn, 256, 256, 0);
            GemmDesc ns1_d = mkDesc(PK(upd_node + 512), 640, 128, nullptr, 0, 0,
                                    WT + WT_NS1, WTL + WT_NS1, 128, ns_b1,
                                    B_thid_n, 64, VNn, 128, 64, FL_RELU | FL_OUTPK);
            gemm2(stream, qs_d, ns1_d);
            // ---- es1 with folded msgs (dedicated kernel) ----
            gemm_es1msgs_kernel<<<dim3(1, VEe / 128), 256, 0, stream>>>(
                PK(A_ec2), B_Qs, from_idx, to_idx,
                WT + WT_ES1, WTL + WT_ES1, es_b1, PK(B_thid_e));
            // ---- es2 || ns2 ----
            GemmDesc es2_d = mkDesc(PK(B_thid_e), 64, 64, nullptr, 0, 0,
                                    WT + WT_ES2, WTL + WT_ES2, 64, es_b2,
                                    B_ttreal_e, 64, VEe, 128, 64, 0);
            GemmDesc ns2_d = mkDesc(PK(B_thid_n), 64, 64, nullptr, 0, 0,
                                    WT + WT_NS2, WTL + WT_NS2, 64, ns_b2,
                                    B_ttreal_n, 64, VNn, 128, 64, 0);
            gemm2(stream, es2_d, ns2_d);
            // ---- merged la: node la+sinkhorn64 (64 blocks) + edge la (1024) ----
            la_fused_kernel<<<64 + 1024, 256, 0, stream>>>(B_ttreal_n, PK(n_la), B_ttreal_e, B_ela);
            sinkhorn256_kernel<<<Bb, 1024, 0, stream>>>(B_ela);
            bgemmDual(stream, PK(n_la), 64, 48, PK(upd_node), 640, PK(node_store), 512, 512);
            // ---- sl loop, Qs ping-pong pipelined under ec2msgs ----
            float* qsbuf[2] = { B_Qs2, B_Qs };
            GemmDesc qs1_d = mkDesc(PK(upd_node), 640, 128, nullptr, 0, 0,
                                    WT + WT_WSUM, WTL + WT_WSUM, 128, nullptr,
                                    qsbuf[0], 256, VNn, 256, 256, 0);
            gemm1(stream, qs1_d);
            for (int sl = 1; sl <= 4; sl++) {
                const size_t ss = (k == 0) ? 0 : (size_t)(sl - 1);
                GemmDesc em_d = mkDesc(PK(ecomb + ss * VEe * 128), 128, 128, nullptr, 0, 0,
                                       WT + WT_MSG + 256, WTL + WT_MSG + 256, 384, msg_b,
                                       B_msgs, 256, VEe, 256, 256, FL_MSGS);
                em_d.qs = qsbuf[(sl - 1) & 1];
                em_d.fidx = from_idx; em_d.tidx = to_idx;
                if (sl < 4) {
                    GemmDesc qsn_d = mkDesc(PK(upd_node + (size_t)sl * 128), 640, 128,
                                            nullptr, 0, 0,
                                            WT + WT_WSUM, WTL + WT_WSUM, 128, nullptr,
                                            qsbuf[sl & 1], 256, VNn, 256, 256, 0);
                    gemm2(stream, em_d, qsn_d);
                } else {
                    gemm1(stream, em_d);
                }
                bgemmDual(stream, PK(B_ela), 256, 192, PK(B_msgs), 256,
                          PK(edge_store + (size_t)(sl - 1) * 256), 1024, 256);
            }
        } else {
            // ---- last k: node transport only ----
            gemmPK(stream, 64, 64, PK(upd_node + 512), 640, 128, nullptr, 0, 0,
                   WT + WT_NS1, WTL + WT_NS1, 128,
                   ns_b1, B_thid_n, 64, VNn, 64, 64, FL_RELU | FL_OUTPK);
            gemmPK(stream, 64, 64, PK(B_thid_n), 64, 64, nullptr, 0, 0,
                   WT + WT_NS2, WTL + WT_NS2, 64,
                   ns_b2, B_ttreal_n, 64, VNn, 64, 64, 0);
            la_fused_kernel<<<64, 256, 0, stream>>>(B_ttreal_n, PK(n_la), B_ttreal_e, B_ela);
        }
    }
    score_kernel<<<Bb, 128, 0, stream>>>(PK(upd_node), PK(n_la), (float*)d_out);
}

// Round 7
// 2785.913 us; speedup vs baseline: 1.0565x; 1.0565x over previous
//
#include <hip/hip_runtime.h>
#include <cstdint>
#include <cstddef>

// Problem constants (from reference)
#define NGg   128     // 2*B
#define Bb    64
#define Nn    48
#define Ee    192
#define Sdim  64
#define VNn   6144    // NGg*Nn
#define VEe   24576   // NGg*Ee
#define INV_TEMP 10.0f
#define ADJ_STRIDE 96

typedef unsigned short u16;
typedef unsigned int   u32;
typedef __attribute__((ext_vector_type(8))) short short8;
typedef __attribute__((ext_vector_type(4))) float floatx4;

// round-to-nearest-even fp32 -> bf16
__device__ __forceinline__ u16 f2bf(float f)
{
    unsigned int u = __float_as_uint(f);
    u += 0x7FFFu + ((u >> 16) & 1u);
    return (u16)(u >> 16);
}
__device__ __forceinline__ float bf2f(u16 h)
{
    return __uint_as_float(((unsigned int)h) << 16);
}

// Packed split-bf16 activation: u32 = hi_bf16 | (lo_bf16 << 16), v ~= hi+lo.
__device__ __forceinline__ u32 packhl(float v)
{
    u16 h = f2bf(v);
    u16 l = f2bf(v - bf2f(h));
    return (u32)h | ((u32)l << 16);
}
__device__ __forceinline__ float unpackhl(u32 w)
{
    return __uint_as_float(w << 16) + __uint_as_float(w & 0xFFFF0000u);
}

// flags bits
#define FL_RELU  1
#define FL_OUTPK 4
#define FL_MSGS  8   // msgs epilogue: pack(2*(acc+bias) + qs[f]+qs[t])

#define TW 40

// ---------------------------------------------------------------------------
// Split-precision bf16x3 MFMA GEMM, packed-hl A operand, templated tile.
// ---------------------------------------------------------------------------
template<int BM, int BN>
__global__ __launch_bounds__(256) void gemm_pk_kernel(
    const u32* __restrict__ A1, int lda1, int K1,
    const u32* __restrict__ A2, int lda2, int K2,
    const u16* __restrict__ Wh, const u16* __restrict__ Wl, int ldwt,
    const float* __restrict__ bias,
    void* __restrict__ Cv, int ldc,
    int Ncap, int flags)
{
    constexpr int FM = BM / 32;
    constexpr int FN = BN / 32;
    constexpr int NA = BM / 8;
    constexpr int NB = BN / 8;
    __shared__ __align__(16) u16 Ah[BM * TW];
    __shared__ __align__(16) u16 Al[BM * TW];
    __shared__ __align__(16) u16 Bh[BN * TW];
    __shared__ __align__(16) u16 Bl[BN * TW];
    const int tid = threadIdx.x;
    const int lane = tid & 63, wave = tid >> 6;
    const int wm = wave >> 1, wn = wave & 1;
    const int bm = blockIdx.y * BM, bn = blockIdx.x * BN;
    const int K = K1 + K2;
    const int AR  = (BM == 128) ? (tid >> 1) : (tid >> 2);
    const int AKo = (BM == 128) ? ((tid & 1) * 16) : ((tid & 3) * 8);
    const int BR  = (BN == 128) ? (tid >> 1) : (tid >> 2);
    const int BKo = (BN == 128) ? ((tid & 1) * 16) : ((tid & 3) * 8);
    const int arow = bm + AR;
    const int brow = bn + BR;
    const int l15 = lane & 15, lq = lane >> 4;

    floatx4 acc[FM][FN];
    #pragma unroll
    for (int i = 0; i < FM; i++)
        #pragma unroll
        for (int j = 0; j < FN; j++) acc[i][j] = (floatx4){0.f, 0.f, 0.f, 0.f};

    for (int k0 = 0; k0 < K; k0 += 32) {
        {
            const int kk = k0 + BKo;
            const u16* bh = Wh + (size_t)brow * ldwt + kk;
            const u16* bl = Wl + (size_t)brow * ldwt + kk;
            #pragma unroll
            for (int q = 0; q < NB / 8; q++) {
                *(uint4*)&Bh[BR * TW + BKo + q * 8] = ((const uint4*)bh)[q];
                *(uint4*)&Bl[BR * TW + BKo + q * 8] = ((const uint4*)bl)[q];
            }
        }
        {
            const int kk = k0 + AKo;
            const u32* asrc = (kk < K1) ? A1 + (size_t)arow * lda1 + kk
                                        : A2 + (size_t)arow * lda2 + (kk - K1);
            u32 pk[NA];
            #pragma unroll
            for (int q = 0; q < NA / 4; q++)
                ((uint4*)pk)[q] = ((const uint4*)asrc)[q];
            u32 hi[NA / 2], lo[NA / 2];
            #pragma unroll
            for (int q = 0; q < NA / 2; q++) {
                hi[q] = __builtin_amdgcn_perm(pk[2 * q + 1], pk[2 * q], 0x05040100u);
                lo[q] = __builtin_amdgcn_perm(pk[2 * q + 1], pk[2 * q], 0x07060302u);
            }
            #pragma unroll
            for (int q = 0; q < NA / 8; q++) {
                *(uint4*)&Ah[AR * TW + AKo + q * 8] = ((uint4*)hi)[q];
                *(uint4*)&Al[AR * TW + AKo + q * 8] = ((uint4*)lo)[q];
            }
        }
        __syncthreads();
        short8 afh[FM], afl[FM], bfh[FN], bfl[FN];
        #pragma unroll
        for (int i = 0; i < FM; i++) {
            const int ro = (wm * (BM / 2) + i * 16 + l15) * TW + lq * 8;
            afh[i] = *(const short8*)&Ah[ro];
            afl[i] = *(const short8*)&Al[ro];
        }
        #pragma unroll
        for (int j = 0; j < FN; j++) {
            const int ro = (wn * (BN / 2) + j * 16 + l15) * TW + lq * 8;
            bfh[j] = *(const short8*)&Bh[ro];
            bfl[j] = *(const short8*)&Bl[ro];
        }
        #pragma unroll
        for (int i = 0; i < FM; i++)
            #pragma unroll
            for (int j = 0; j < FN; j++) {
                acc[i][j] = __builtin_amdgcn_mfma_f32_16x16x32_bf16(afh[i], bfl[j], acc[i][j], 0, 0, 0);
                acc[i][j] = __builtin_amdgcn_mfma_f32_16x16x32_bf16(afl[i], bfh[j], acc[i][j], 0, 0, 0);
                acc[i][j] = __builtin_amdgcn_mfma_f32_16x16x32_bf16(afh[i], bfh[j], acc[i][j], 0, 0, 0);
            }
        __syncthreads();
    }
    const int relu = flags & FL_RELU;
    const int opk  = flags & FL_OUTPK;
    #pragma unroll
    for (int j = 0; j < FN; j++) {
        const int col = bn + wn * (BN / 2) + j * 16 + l15;
        const bool cok = (col < Ncap);
        const float bv = (bias && cok) ? bias[col] : 0.f;
        #pragma unroll
        for (int i = 0; i < FM; i++) {
            const int row0 = bm + wm * (BM / 2) + i * 16 + lq * 4;
            #pragma unroll
            for (int r = 0; r < 4; r++) {
                float v = acc[i][j][r] + bv;
                if (relu) v = fmaxf(v, 0.f);
                if (cok) {
                    if (opk)
                        ((u32*)Cv)[(size_t)(row0 + r) * ldc + col] = packhl(v);
                    else
                        ((float*)Cv)[(size_t)(row0 + r) * ldc + col] = v;
                }
            }
        }
    }
}

static inline void gemmPK(hipStream_t s, int BM, int BN,
                          const u32* A1, int lda1, int K1,
                          const u32* A2, int lda2, int K2,
                          const u16* Wh, const u16* Wl, int ldwt,
                          const float* bias,
                          void* C, int ldc, int M, int Ngrid, int Ncap, int flags)
{
    dim3 grid(Ngrid / BN, M / BM);
    if (BM == 128 && BN == 128)
        gemm_pk_kernel<128, 128><<<grid, 256, 0, s>>>(A1, lda1, K1, A2, lda2, K2, Wh, Wl, ldwt, bias, C, ldc, Ncap, flags);
    else if (BM == 128 && BN == 64)
        gemm_pk_kernel<128, 64><<<grid, 256, 0, s>>>(A1, lda1, K1, A2, lda2, K2, Wh, Wl, ldwt, bias, C, ldc, Ncap, flags);
    else if (BM == 64 && BN == 128)
        gemm_pk_kernel<64, 128><<<grid, 256, 0, s>>>(A1, lda1, K1, A2, lda2, K2, Wh, Wl, ldwt, bias, C, ldc, Ncap, flags);
    else
        gemm_pk_kernel<64, 64><<<grid, 256, 0, s>>>(A1, lda1, K1, A2, lda2, K2, Wh, Wl, ldwt, bias, C, ldc, Ncap, flags);
}

// ---------------------------------------------------------------------------
// Dual-GEMM fused dispatch (128x128 tiles), FL_MSGS epilogue variant kept.
// ---------------------------------------------------------------------------
struct GemmDesc {
    const u32* A1; int lda1, K1;
    const u32* A2; int lda2, K2;
    const u16* Wh; const u16* Wl; int ldwt;
    const float* bias;
    void* C; int ldc;
    int Ncap, flags, nx, nblk;
    const float* qs;            // FL_MSGS only
    const int* fidx; const int* tidx;
};

static inline GemmDesc mkDesc(const u32* A1, int lda1, int K1,
                              const u32* A2, int lda2, int K2,
                              const u16* Wh, const u16* Wl, int ldwt,
                              const float* bias, void* C, int ldc,
                              int M, int Ngrid, int Ncap, int flags)
{
    GemmDesc d;
    d.A1 = A1; d.lda1 = lda1; d.K1 = K1;
    d.A2 = A2; d.lda2 = lda2; d.K2 = K2;
    d.Wh = Wh; d.Wl = Wl; d.ldwt = ldwt;
    d.bias = bias; d.C = C; d.ldc = ldc;
    d.Ncap = Ncap; d.flags = flags;
    d.nx = Ngrid / 128; d.nblk = (M / 128) * (Ngrid / 128);
    d.qs = nullptr; d.fidx = nullptr; d.tidx = nullptr;
    return d;
}

__global__ __launch_bounds__(256) void gemm2_pk_kernel(GemmDesc d0, GemmDesc d1, int nb0)
{
    GemmDesc d;
    int local;
    if ((int)blockIdx.x < nb0) { d = d0; local = blockIdx.x; }
    else                       { d = d1; local = blockIdx.x - nb0; }
    const int by = local / d.nx, bx = local % d.nx;
    __shared__ __align__(16) u16 Ah[128 * TW];
    __shared__ __align__(16) u16 Al[128 * TW];
    __shared__ __align__(16) u16 Bh[128 * TW];
    __shared__ __align__(16) u16 Bl[128 * TW];
    const int tid = threadIdx.x;
    const int lane = tid & 63, wave = tid >> 6;
    const int wm = wave >> 1, wn = wave & 1;
    const int bm = by * 128, bn = bx * 128;
    const int K = d.K1 + d.K2;
    const int srow = tid >> 1;
    const int skoff = (tid & 1) * 16;
    const int arow = bm + srow;
    const int brow = bn + srow;
    const int l15 = lane & 15, lq = lane >> 4;

    floatx4 acc[4][4];
    #pragma unroll
    for (int i = 0; i < 4; i++)
        #pragma unroll
        for (int j = 0; j < 4; j++) acc[i][j] = (floatx4){0.f, 0.f, 0.f, 0.f};

    for (int k0 = 0; k0 < K; k0 += 32) {
        {
            const int kk = k0 + skoff;
            const u16* bh = d.Wh + (size_t)brow * d.ldwt + kk;
            const u16* bl = d.Wl + (size_t)brow * d.ldwt + kk;
            *(uint4*)&Bh[srow * TW + skoff]     = ((const uint4*)bh)[0];
            *(uint4*)&Bh[srow * TW + skoff + 8] = ((const uint4*)bh)[1];
            *(uint4*)&Bl[srow * TW + skoff]     = ((const uint4*)bl)[0];
            *(uint4*)&Bl[srow * TW + skoff + 8] = ((const uint4*)bl)[1];
        }
        {
            const int kk = k0 + skoff;
            const u32* asrc = (kk < d.K1) ? d.A1 + (size_t)arow * d.lda1 + kk
                                          : d.A2 + (size_t)arow * d.lda2 + (kk - d.K1);
            u32 pk[16];
            ((uint4*)pk)[0] = ((const uint4*)asrc)[0];
            ((uint4*)pk)[1] = ((const uint4*)asrc)[1];
            ((uint4*)pk)[2] = ((const uint4*)asrc)[2];
            ((uint4*)pk)[3] = ((const uint4*)asrc)[3];
            u32 hi[8], lo[8];
            #pragma unroll
            for (int q = 0; q < 8; q++) {
                hi[q] = __builtin_amdgcn_perm(pk[2 * q + 1], pk[2 * q], 0x05040100u);
                lo[q] = __builtin_amdgcn_perm(pk[2 * q + 1], pk[2 * q], 0x07060302u);
            }
            *(uint4*)&Ah[srow * TW + skoff]     = ((uint4*)hi)[0];
            *(uint4*)&Ah[srow * TW + skoff + 8] = ((uint4*)hi)[1];
            *(uint4*)&Al[srow * TW + skoff]     = ((uint4*)lo)[0];
            *(uint4*)&Al[srow * TW + skoff + 8] = ((uint4*)lo)[1];
        }
        __syncthreads();
        short8 afh[4], afl[4], bfh[4], bfl[4];
        #pragma unroll
        for (int i = 0; i < 4; i++) {
            const int ro = (wm * 64 + i * 16 + l15) * TW + lq * 8;
            afh[i] = *(const short8*)&Ah[ro];
            afl[i] = *(const short8*)&Al[ro];
        }
        #pragma unroll
        for (int j = 0; j < 4; j++) {
            const int ro = (wn * 64 + j * 16 + l15) * TW + lq * 8;
            bfh[j] = *(const short8*)&Bh[ro];
            bfl[j] = *(const short8*)&Bl[ro];
        }
        #pragma unroll
        for (int i = 0; i < 4; i++)
            #pragma unroll
            for (int j = 0; j < 4; j++) {
                acc[i][j] = __builtin_amdgcn_mfma_f32_16x16x32_bf16(afh[i], bfl[j], acc[i][j], 0, 0, 0);
                acc[i][j] = __builtin_amdgcn_mfma_f32_16x16x32_bf16(afl[i], bfh[j], acc[i][j], 0, 0, 0);
                acc[i][j] = __builtin_amdgcn_mfma_f32_16x16x32_bf16(afh[i], bfh[j], acc[i][j], 0, 0, 0);
            }
        __syncthreads();
    }
    if (d.flags & FL_MSGS) {
        #pragma unroll
        for (int i = 0; i < 4; i++) {
            #pragma unroll
            for (int r = 0; r < 4; r++) {
                const int row = bm + wm * 64 + i * 16 + lq * 4 + r;
                const int fi = d.fidx[row], ti = d.tidx[row];
                #pragma unroll
                for (int j = 0; j < 4; j++) {
                    const int col = bn + wn * 64 + j * 16 + l15;
                    float v = 2.f * (acc[i][j][r] + d.bias[col])
                            + d.qs[(size_t)fi * 256 + col] + d.qs[(size_t)ti * 256 + col];
                    ((u32*)d.C)[(size_t)row * d.ldc + col] = packhl(v);
                }
            }
        }
        return;
    }
    const int relu = d.flags & FL_RELU;
    const int opk  = d.flags & FL_OUTPK;
    #pragma unroll
    for (int j = 0; j < 4; j++) {
        const int col = bn + wn * 64 + j * 16 + l15;
        const bool cok = (col < d.Ncap);
        const float bv = (d.bias && cok) ? d.bias[col] : 0.f;
        #pragma unroll
        for (int i = 0; i < 4; i++) {
            const int row0 = bm + wm * 64 + i * 16 + lq * 4;
            #pragma unroll
            for (int r = 0; r < 4; r++) {
                float v = acc[i][j][r] + bv;
                if (relu) v = fmaxf(v, 0.f);
                if (cok) {
                    if (opk)
                        ((u32*)d.C)[(size_t)(row0 + r) * d.ldc + col] = packhl(v);
                    else
                        ((float*)d.C)[(size_t)(row0 + r) * d.ldc + col] = v;
                }
            }
        }
    }
}

static inline void gemm2(hipStream_t s, const GemmDesc& d0, const GemmDesc& d1)
{
    gemm2_pk_kernel<<<d0.nblk + d1.nblk, 256, 0, s>>>(d0, d1, d0.nblk);
}
static inline void gemm1(hipStream_t s, const GemmDesc& d0)
{
    gemm2_pk_kernel<<<d0.nblk, 256, 0, s>>>(d0, d0, d0.nblk);
}

// ---------------------------------------------------------------------------
// es1 GEMM with the msgs transform folded into A-staging. BM=128, BN=64.
//   A_eff[row][c] = qs[f[row]][c] + qs[t[row]][c] + 2*unpackhl(ec2[row][c])
// ---------------------------------------------------------------------------
__global__ __launch_bounds__(256) void gemm_es1msgs_kernel(
    const u32* __restrict__ A,
    const float* __restrict__ qs,
    const int* __restrict__ fidx, const int* __restrict__ tidx,
    const u16* __restrict__ Wh, const u16* __restrict__ Wl,
    const float* __restrict__ bias,
    u32* __restrict__ C)
{
    __shared__ __align__(16) u16 Ah[128 * TW];
    __shared__ __align__(16) u16 Al[128 * TW];
    __shared__ __align__(16) u16 Bh[64 * TW];
    __shared__ __align__(16) u16 Bl[64 * TW];
    const int tid = threadIdx.x;
    const int lane = tid & 63, wave = tid >> 6;
    const int wm = wave >> 1, wn = wave & 1;
    const int bm = blockIdx.y * 128;
    const int AR = tid >> 1, AKo = (tid & 1) * 16;
    const int BR = tid >> 2, BKo = (tid & 3) * 8;
    const int arow = bm + AR;
    const int l15 = lane & 15, lq = lane >> 4;
    const int fi = fidx[arow], ti = tidx[arow];

    floatx4 acc[4][2];
    #pragma unroll
    for (int i = 0; i < 4; i++)
        #pragma unroll
        for (int j = 0; j < 2; j++) acc[i][j] = (floatx4){0.f, 0.f, 0.f, 0.f};

    for (int k0 = 0; k0 < 256; k0 += 32) {
        {
            const int kk = k0 + BKo;
            const u16* bh = Wh + (size_t)BR * 256 + kk;
            const u16* bl = Wl + (size_t)BR * 256 + kk;
            *(uint4*)&Bh[BR * TW + BKo] = ((const uint4*)bh)[0];
            *(uint4*)&Bl[BR * TW + BKo] = ((const uint4*)bl)[0];
        }
        {
            const int kk = k0 + AKo;
            const u32* asrc = A + (size_t)arow * 256 + kk;
            u32 pk[16];
            ((uint4*)pk)[0] = ((const uint4*)asrc)[0];
            ((uint4*)pk)[1] = ((const uint4*)asrc)[1];
            ((uint4*)pk)[2] = ((const uint4*)asrc)[2];
            ((uint4*)pk)[3] = ((const uint4*)asrc)[3];
            float qf[16], qt[16];
            const float* qfp = qs + (size_t)fi * 256 + kk;
            const float* qtp = qs + (size_t)ti * 256 + kk;
            #pragma unroll
            for (int q = 0; q < 4; q++) {
                ((float4*)qf)[q] = ((const float4*)qfp)[q];
                ((float4*)qt)[q] = ((const float4*)qtp)[q];
            }
            u16 ph[16], pl8[16];
            #pragma unroll
            for (int q = 0; q < 16; q++) {
                float v = qf[q] + qt[q] + 2.f * unpackhl(pk[q]);
                u16 h = f2bf(v);
                ph[q] = h;
                pl8[q] = f2bf(v - bf2f(h));
            }
            *(uint4*)&Ah[AR * TW + AKo]     = *(const uint4*)&ph[0];
            *(uint4*)&Ah[AR * TW + AKo + 8] = *(const uint4*)&ph[8];
            *(uint4*)&Al[AR * TW + AKo]     = *(const uint4*)&pl8[0];
            *(uint4*)&Al[AR * TW + AKo + 8] = *(const uint4*)&pl8[8];
        }
        __syncthreads();
        short8 afh[4], afl[4], bfh[2], bfl[2];
        #pragma unroll
        for (int i = 0; i < 4; i++) {
            const int ro = (wm * 64 + i * 16 + l15) * TW + lq * 8;
            afh[i] = *(const short8*)&Ah[ro];
            afl[i] = *(const short8*)&Al[ro];
        }
        #pragma unroll
        for (int j = 0; j < 2; j++) {
            const int ro = (wn * 32 + j * 16 + l15) * TW + lq * 8;
            bfh[j] = *(const short8*)&Bh[ro];
            bfl[j] = *(const short8*)&Bl[ro];
        }
        #pragma unroll
        for (int i = 0; i < 4; i++)
            #pragma unroll
            for (int j = 0; j < 2; j++) {
                acc[i][j] = __builtin_amdgcn_mfma_f32_16x16x32_bf16(afh[i], bfl[j], acc[i][j], 0, 0, 0);
                acc[i][j] = __builtin_amdgcn_mfma_f32_16x16x32_bf16(afl[i], bfh[j], acc[i][j], 0, 0, 0);
                acc[i][j] = __builtin_amdgcn_mfma_f32_16x16x32_bf16(afh[i], bfh[j], acc[i][j], 0, 0, 0);
            }
        __syncthreads();
    }
    #pragma unroll
    for (int j = 0; j < 2; j++) {
        const int col = wn * 32 + j * 16 + l15;
        const float bv = bias[col];
        #pragma unroll
        for (int i = 0; i < 4; i++) {
            const int row0 = bm + wm * 64 + i * 16 + lq * 4;
            #pragma unroll
            for (int r = 0; r < 4; r++) {
                float v = fmaxf(acc[i][j][r] + bv, 0.f);
                C[(size_t)(row0 + r) * 64 + col] = packhl(v);
            }
        }
    }
}

// ---------------------------------------------------------------------------
// fp32-A GEMM for the two encoder calls only (K=32), BM=BN=128, packed out.
// ---------------------------------------------------------------------------
__global__ __launch_bounds__(256) void gemm_f32_kernel(
    const float* __restrict__ A, int lda, int K,
    const u16* __restrict__ Wh, const u16* __restrict__ Wl, int ldwt,
    const float* __restrict__ bias, u32* __restrict__ C, int ldc, int Ncap)
{
    __shared__ __align__(16) u16 Ah[128 * TW];
    __shared__ __align__(16) u16 Al[128 * TW];
    __shared__ __align__(16) u16 Bh[128 * TW];
    __shared__ __align__(16) u16 Bl[128 * TW];
    const int tid = threadIdx.x;
    const int lane = tid & 63, wave = tid >> 6;
    const int wm = wave >> 1, wn = wave & 1;
    const int bm = blockIdx.y * 128, bn = blockIdx.x * 128;
    const int srow = tid >> 1;
    const int skoff = (tid & 1) * 16;
    const int arow = bm + srow, brow = bn + srow;
    const int l15 = lane & 15, lq = lane >> 4;

    floatx4 acc[4][4];
    #pragma unroll
    for (int i = 0; i < 4; i++)
        #pragma unroll
        for (int j = 0; j < 4; j++) acc[i][j] = (floatx4){0.f, 0.f, 0.f, 0.f};

    for (int k0 = 0; k0 < K; k0 += 32) {
        const int kk = k0 + skoff;
        const float* asrc = A + (size_t)arow * lda + kk;
        float f[16];
        ((float4*)f)[0] = ((const float4*)asrc)[0];
        ((float4*)f)[1] = ((const float4*)asrc)[1];
        ((float4*)f)[2] = ((const float4*)asrc)[2];
        ((float4*)f)[3] = ((const float4*)asrc)[3];
        u16 ph[16], pl8[16];
        #pragma unroll
        for (int q = 0; q < 16; q++) {
            u16 h = f2bf(f[q]);
            ph[q] = h;
            pl8[q] = f2bf(f[q] - bf2f(h));
        }
        *(uint4*)&Ah[srow * TW + skoff]     = *(const uint4*)&ph[0];
        *(uint4*)&Ah[srow * TW + skoff + 8] = *(const uint4*)&ph[8];
        *(uint4*)&Al[srow * TW + skoff]     = *(const uint4*)&pl8[0];
        *(uint4*)&Al[srow * TW + skoff + 8] = *(const uint4*)&pl8[8];
        const u16* bh = Wh + (size_t)brow * ldwt + kk;
        const u16* bl = Wl + (size_t)brow * ldwt + kk;
        *(uint4*)&Bh[srow * TW + skoff]     = ((const uint4*)bh)[0];
        *(uint4*)&Bh[srow * TW + skoff + 8] = ((const uint4*)bh)[1];
        *(uint4*)&Bl[srow * TW + skoff]     = ((const uint4*)bl)[0];
        *(uint4*)&Bl[srow * TW + skoff + 8] = ((const uint4*)bl)[1];
        __syncthreads();
        short8 afh[4], afl[4], bfh[4], bfl[4];
        #pragma unroll
        for (int i = 0; i < 4; i++) {
            const int ro = (wm * 64 + i * 16 + l15) * TW + lq * 8;
            afh[i] = *(const short8*)&Ah[ro];
            afl[i] = *(const short8*)&Al[ro];
        }
        #pragma unroll
        for (int j = 0; j < 4; j++) {
            const int ro = (wn * 64 + j * 16 + l15) * TW + lq * 8;
            bfh[j] = *(const short8*)&Bh[ro];
            bfl[j] = *(const short8*)&Bl[ro];
        }
        #pragma unroll
        for (int i = 0; i < 4; i++)
            #pragma unroll
            for (int j = 0; j < 4; j++) {
                acc[i][j] = __builtin_amdgcn_mfma_f32_16x16x32_bf16(afh[i], bfl[j], acc[i][j], 0, 0, 0);
                acc[i][j] = __builtin_amdgcn_mfma_f32_16x16x32_bf16(afl[i], bfh[j], acc[i][j], 0, 0, 0);
                acc[i][j] = __builtin_amdgcn_mfma_f32_16x16x32_bf16(afh[i], bfh[j], acc[i][j], 0, 0, 0);
            }
        __syncthreads();
    }
    #pragma unroll
    for (int j = 0; j < 4; j++) {
        const int col = bn + wn * 64 + j * 16 + l15;
        const bool cok = (col < Ncap);
        const float bv = cok ? bias[col] : 0.f;
        #pragma unroll
        for (int i = 0; i < 4; i++) {
            const int row0 = bm + wm * 64 + i * 16 + lq * 4;
            #pragma unroll
            for (int r = 0; r < 4; r++) {
                if (cok)
                    C[(size_t)(row0 + r) * ldc + col] = packhl(acc[i][j][r] + bv);
            }
        }
    }
}

// ---------------------------------------------------------------------------
// One-shot weight prep (all transposed hi/lo bf16 planes; Wsum inline).
// ---------------------------------------------------------------------------
__global__ __launch_bounds__(256) void prep_kernel(
    const float* __restrict__ niW1, const float* __restrict__ niW2,
    const float* __restrict__ eiW1, const float* __restrict__ eiW2,
    const float* __restrict__ msgW, const float* __restrict__ nuW1,
    const float* __restrict__ nuW2, const float* __restrict__ encnW,
    const float* __restrict__ enceW, const float* __restrict__ nsW1,
    const float* __restrict__ nsW2, const float* __restrict__ esW1,
    const float* __restrict__ esW2,
    u16* __restrict__ WT, u16* __restrict__ WTL)
{
    int idx = blockIdx.x * 256 + threadIdx.x;
    if (idx >= 696320) return;
    const float* src; int base, N, Npad, ldk, noff = 0, wtoff;
    int wsum = 0;
    if      (idx < 65536)  { src = niW1;  base = 0;      N = 256; Npad = 256; ldk = 256; wtoff = 0; }
    else if (idx < 98304)  { src = niW2;  base = 65536;  N = 128; Npad = 128; ldk = 256; wtoff = 65536; }
    else if (idx < 245760) { src = eiW1;  base = 98304;  N = 384; Npad = 384; ldk = 384; wtoff = 98304; }
    else if (idx < 294912) { src = eiW2;  base = 245760; N = 128; Npad = 128; ldk = 384; wtoff = 245760; }
    else if (idx < 393216) { src = msgW;  base = 294912; N = 256; Npad = 256; ldk = 384; wtoff = 294912; }
    else if (idx < 425984) { src = msgW;  base = 393216; N = 256; Npad = 256; ldk = 128; wtoff = 393216; }
    else if (idx < 458752) { src = msgW + 32768; base = 425984; N = 256; Npad = 256; ldk = 128; noff = 256; wtoff = 393216; }
    else if (idx < 557056) { src = nuW1;  base = 458752; N = 256; Npad = 256; ldk = 384; wtoff = 458752; }
    else if (idx < 589824) { src = nuW2;  base = 557056; N = 128; Npad = 128; ldk = 256; wtoff = 557056; }
    else if (idx < 622592) { src = msgW;  base = 589824; N = 256; Npad = 256; ldk = 128; wtoff = 589824; wsum = 1; }
    else if (idx < 626688) { src = encnW; base = 622592; N = 128; Npad = 128; ldk = 32;  wtoff = 622592; }
    else if (idx < 630784) { src = enceW; base = 626688; N = 128; Npad = 128; ldk = 32;  wtoff = 626688; }
    else if (idx < 647168) { src = nsW1;  base = 630784; N = 64;  Npad = 128; ldk = 128; wtoff = 630784; }
    else if (idx < 655360) { src = nsW2;  base = 647168; N = 64;  Npad = 128; ldk = 64;  wtoff = 647168; }
    else if (idx < 688128) { src = esW1;  base = 655360; N = 64;  Npad = 128; ldk = 256; wtoff = 655360; }
    else                   { src = esW2;  base = 688128; N = 64;  Npad = 128; ldk = 64;  wtoff = 688128; }
    int rel = idx - base;
    int k = rel / Npad, n = rel % Npad;
    float v = 0.f;
    if (n < N) {
        v = src[(size_t)k * N + n];
        if (wsum) v += src[32768 + (size_t)k * N + n];
    }
    u16 h = f2bf(v);
    size_t o = (size_t)wtoff + (size_t)(noff + n) * ldk + k;
    WT[o] = h;
    WTL[o] = f2bf(v - bf2f(h));
}

// ---------------------------------------------------------------------------
// Dual batched MFMA plan-GEMM: qi (transp=0) + ci (transp=1) in one launch.
// P PACKED-hl; U packed-hl; C packed-hl.
// ---------------------------------------------------------------------------
__global__ __launch_bounds__(256) void bgemm_dual_kernel(
    const u32* __restrict__ P, int ms, int n_per,
    const u32* __restrict__ U, int ldu,
    u32* __restrict__ C, int ldc, int nxh)
{
    __shared__ __align__(16) u16 Ah[64 * TW];
    __shared__ __align__(16) u16 Al[64 * TW];
    __shared__ __align__(16) u16 Bh[128 * TW];
    __shared__ __align__(16) u16 Bl[128 * TW];
    const int b = blockIdx.z;
    const u32* Pb = P + (size_t)b * ms * ms;
    const int bxr = blockIdx.x;
    const int transp = (bxr >= nxh) ? 1 : 0;
    const int bn = (bxr - transp * nxh) * 128;
    const int qbase = (2 * b) * n_per, cbase = (2 * b + 1) * n_per;
    const int obase = transp ? cbase : qbase;
    const int ibase = transp ? qbase : cbase;
    const int bm = blockIdx.y * 64;
    const int tid = threadIdx.x, lane = tid & 63, wave = tid >> 6;
    const int wm = wave >> 1, wn = wave & 1;
    const int l15 = lane & 15, lq = lane >> 4;
    const int sar = tid >> 2, sak = (tid & 3) * 8;
    const int sbn = tid >> 1, sbk = (tid & 1) * 16;
    const int Kpad = (n_per + 31) & ~31;

    floatx4 acc[2][4];
    #pragma unroll
    for (int i = 0; i < 2; i++)
        #pragma unroll
        for (int j = 0; j < 4; j++) acc[i][j] = (floatx4){0.f, 0.f, 0.f, 0.f};

    for (int k0 = 0; k0 < Kpad; k0 += 32) {
        {
            const int m = bm + sar;
            u32 pk[8];
            if (m < n_per) {
                if (!transp) {
                    const u32* src = Pb + (size_t)m * ms + k0 + sak;
                    ((uint4*)pk)[0] = ((const uint4*)src)[0];
                    ((uint4*)pk)[1] = ((const uint4*)src)[1];
                } else {
                    #pragma unroll
                    for (int i = 0; i < 8; i++)
                        pk[i] = Pb[(size_t)(k0 + sak + i) * ms + m];
                }
                #pragma unroll
                for (int i = 0; i < 8; i++)
                    if (k0 + sak + i >= n_per) pk[i] = 0;
            } else {
                #pragma unroll
                for (int i = 0; i < 8; i++) pk[i] = 0;
            }
            u32 hi[4], lo[4];
            #pragma unroll
            for (int q = 0; q < 4; q++) {
                hi[q] = __builtin_amdgcn_perm(pk[2 * q + 1], pk[2 * q], 0x05040100u);
                lo[q] = __builtin_amdgcn_perm(pk[2 * q + 1], pk[2 * q], 0x07060302u);
            }
            *(uint4*)&Ah[sar * TW + sak] = *(uint4*)hi;
            *(uint4*)&Al[sar * TW + sak] = *(uint4*)lo;
        }
        {
            u16 qh[16], ql[16];
            #pragma unroll
            for (int i = 0; i < 16; i++) {
                int kk = k0 + sbk + i;
                u32 w = 0;
                if (kk < n_per) w = U[(size_t)(ibase + kk) * ldu + bn + sbn];
                qh[i] = (u16)w; ql[i] = (u16)(w >> 16);
            }
            *(uint4*)&Bh[sbn * TW + sbk]     = *(const uint4*)&qh[0];
            *(uint4*)&Bh[sbn * TW + sbk + 8] = *(const uint4*)&qh[8];
            *(uint4*)&Bl[sbn * TW + sbk]     = *(const uint4*)&ql[0];
            *(uint4*)&Bl[sbn * TW + sbk + 8] = *(const uint4*)&ql[8];
        }
        __syncthreads();
        short8 afh[2], afl[2], bfh[4], bfl[4];
        #pragma unroll
        for (int i = 0; i < 2; i++) {
            const int ro = (wm * 32 + i * 16 + l15) * TW + lq * 8;
            afh[i] = *(const short8*)&Ah[ro];
            afl[i] = *(const short8*)&Al[ro];
        }
        #pragma unroll
        for (int j = 0; j < 4; j++) {
            const int ro = (wn * 64 + j * 16 + l15) * TW + lq * 8;
            bfh[j] = *(const short8*)&Bh[ro];
            bfl[j] = *(const short8*)&Bl[ro];
        }
        #pragma unroll
        for (int i = 0; i < 2; i++)
            #pragma unroll
            for (int j = 0; j < 4; j++) {
                acc[i][j] = __builtin_amdgcn_mfma_f32_16x16x32_bf16(afh[i], bfl[j], acc[i][j], 0, 0, 0);
                acc[i][j] = __builtin_amdgcn_mfma_f32_16x16x32_bf16(afl[i], bfh[j], acc[i][j], 0, 0, 0);
                acc[i][j] = __builtin_amdgcn_mfma_f32_16x16x32_bf16(afh[i], bfh[j], acc[i][j], 0, 0, 0);
            }
        __syncthreads();
    }
    #pragma unroll
    for (int j = 0; j < 4; j++) {
        const int col = bn + wn * 64 + j * 16 + l15;
        #pragma unroll
        for (int i = 0; i < 2; i++) {
            const int row0 = bm + wm * 32 + i * 16 + lq * 4;
            #pragma unroll
            for (int r = 0; r < 4; r++) {
                const int m = row0 + r;
                if (m < n_per)
                    C[(size_t)(obase + m) * ldc + col] = packhl(acc[i][j][r]);
            }
        }
    }
}

static inline void bgemmDual(hipStream_t s, const u32* P, int ms, int n_per,
                             const u32* U, int ldu, u32* C, int ldc, int N)
{
    int nxh = N / 128;
    dim3 grid(nxh * 2, (n_per + 63) / 64, Bb);
    bgemm_dual_kernel<<<grid, 256, 0, s>>>(P, ms, n_per, U, ldu, C, ldc, nxh);
}

// ---------------------------------------------------------------------------
// Merged la dispatch: blocks 0..63 = node la+sinkhorn64 (packed plan out);
// blocks 64..1087 = edge la 256x256 tiles.
// ---------------------------------------------------------------------------
__global__ __launch_bounds__(256) void la_fused_kernel(
    const float* __restrict__ ttn, u32* __restrict__ n_la,
    const float* __restrict__ tte, float* __restrict__ ela)
{
    __shared__ float Aq[64][65];
    __shared__ float Ac[64][65];
    __shared__ float m[64][65];
    __shared__ float v_s[64];
    __shared__ float part[4][64];
    const int tid = threadIdx.x;
    if ((int)blockIdx.x >= 64) {
        // ---- edge la tile ----
        const int id = blockIdx.x - 64;
        const int b = id >> 4;
        const int bm = ((id >> 2) & 3) * 64, bn = (id & 3) * 64;
        for (int idx = tid; idx < 4096; idx += 256) {
            int r = idx >> 6, s = idx & 63;
            float vq = 0.f, vc = 0.f;
            int qr = bm + r, cr = bn + r;
            if (qr < Ee) vq = tte[((size_t)(2 * b) * Ee + qr) * Sdim + s];
            if (cr < Ee) vc = tte[((size_t)(2 * b + 1) * Ee + cr) * Sdim + s];
            Aq[r][s] = vq;
            Ac[r][s] = vc;
        }
        __syncthreads();
        const int tx = tid & 15, ty = tid >> 4;
        float acc[4][4] = {};
        for (int s = 0; s < 64; s++) {
            float a[4], c[4];
            #pragma unroll
            for (int i = 0; i < 4; i++) a[i] = Aq[ty * 4 + i][s];
            #pragma unroll
            for (int j = 0; j < 4; j++) c[j] = Ac[tx * 4 + j][s];
            #pragma unroll
            for (int i = 0; i < 4; i++)
                #pragma unroll
                for (int j = 0; j < 4; j++)
                    acc[i][j] = fmaf(a[i], c[j], acc[i][j]);
        }
        #pragma unroll
        for (int i = 0; i < 4; i++)
            #pragma unroll
            for (int j = 0; j < 4; j++)
                ela[((size_t)b * 256 + bm + ty * 4 + i) * 256 + bn + tx * 4 + j] = acc[i][j] * INV_TEMP;
        return;
    }
    // ---- node la + sinkhorn64 ----
    const int b = blockIdx.x;
    const int lane = tid & 63, w = tid >> 6;
    for (int idx = tid; idx < 4096; idx += 256) {
        int r = idx >> 6, s = idx & 63;
        float vq = 0.f, vc = 0.f;
        if (r < Nn) {
            vq = ttn[((size_t)(2 * b) * Nn + r) * Sdim + s];
            vc = ttn[((size_t)(2 * b + 1) * Nn + r) * Sdim + s];
        }
        Aq[r][s] = vq;
        Ac[r][s] = vc;
    }
    __syncthreads();
    {
        const int tx = tid & 15, ty = tid >> 4;
        float acc[4][4] = {};
        for (int s = 0; s < 64; s++) {
            float a[4], c[4];
            #pragma unroll
            for (int i = 0; i < 4; i++) a[i] = Aq[ty * 4 + i][s];
            #pragma unroll
            for (int j = 0; j < 4; j++) c[j] = Ac[tx * 4 + j][s];
            #pragma unroll
            for (int i = 0; i < 4; i++)
                #pragma unroll
                for (int j = 0; j < 4; j++)
                    acc[i][j] = fmaf(a[i], c[j], acc[i][j]);
        }
        #pragma unroll
        for (int i = 0; i < 4; i++)
            #pragma unroll
            for (int j = 0; j < 4; j++)
                m[ty * 4 + i][tx * 4 + j] = acc[i][j] * INV_TEMP;
    }
    if (tid < 64) v_s[tid] = 0.f;
    __syncthreads();
    float x[16], u[16];
    #pragma unroll
    for (int j = 0; j < 16; j++) x[j] = m[w * 16 + j][lane];
    #pragma unroll
    for (int j = 0; j < 16; j++) {
        float mx = x[j];
        #pragma unroll
        for (int d = 1; d < 64; d <<= 1) mx = fmaxf(mx, __shfl_xor(mx, d));
        u[j] = mx;
    }
    for (int it = 0; it < 10; it++) {
        float vr = v_s[lane];
        #pragma unroll
        for (int j = 0; j < 16; j++) {
            float s = __expf(x[j] - vr - u[j]);
            #pragma unroll
            for (int d = 1; d < 64; d <<= 1) s += __shfl_xor(s, d);
            u[j] += __logf(s);
        }
        float s = 0.f;
        #pragma unroll
        for (int j = 0; j < 16; j++) s += __expf(x[j] - u[j] - vr);
        part[w][lane] = s;
        __syncthreads();
        if (tid < 64) {
            float ss = part[0][tid] + part[1][tid] + part[2][tid] + part[3][tid];
            v_s[tid] += __logf(ss);
        }
        __syncthreads();
    }
    float vr = v_s[lane];
    u32* g = n_la + (size_t)b * 4096;
    #pragma unroll
    for (int j = 0; j < 16; j++)
        g[(size_t)(w * 16 + j) * 64 + lane] = packhl(__expf(x[j] - u[j] - vr));
}

// ---------------------------------------------------------------------------
// Sinkhorn 256x256 with x cached in registers for all 10 iterations.
// MEASURED A/B ON THIS PROBLEM: register-cached (1024,4) = 91-96 us (rounds
// 4/5); streaming re-read form = 127-131 us (rounds 3/6). Keep this one.
// Packed-hl plan epilogue (consumed as u32 by bgemm_dual).
// ---------------------------------------------------------------------------
__global__ __launch_bounds__(1024, 4) void sinkhorn256_kernel(float* __restrict__ la)
{
    const int b = blockIdx.x;
    float* g = la + (size_t)b * 65536;
    const int tid = threadIdx.x;
    const int lane = tid & 63, w = tid >> 6;
    __shared__ float v_s[256];
    __shared__ float part[16][64][5];  // [wave][lane][q], stride-5 pad

    float4 x[16];
    float u[16];
    #pragma unroll
    for (int j = 0; j < 16; j++) {
        x[j] = ((const float4*)(g + (size_t)(w * 16 + j) * 256))[lane];
        float mx = fmaxf(fmaxf(x[j].x, x[j].y), fmaxf(x[j].z, x[j].w));
        #pragma unroll
        for (int d = 1; d < 64; d <<= 1) mx = fmaxf(mx, __shfl_xor(mx, d));
        u[j] = mx;
    }
    if (tid < 256) v_s[tid] = 0.f;
    __syncthreads();

    for (int it = 0; it < 10; it++) {
        const float4 vr = *(const float4*)&v_s[4 * lane];
        float cp0 = 0.f, cp1 = 0.f, cp2 = 0.f, cp3 = 0.f;
        #pragma unroll
        for (int j = 0; j < 16; j++) {
            float e0 = __expf(x[j].x - vr.x - u[j]);
            float e1 = __expf(x[j].y - vr.y - u[j]);
            float e2 = __expf(x[j].z - vr.z - u[j]);
            float e3 = __expf(x[j].w - vr.w - u[j]);
            float s = e0 + e1 + e2 + e3;
            #pragma unroll
            for (int d = 1; d < 64; d <<= 1) s += __shfl_xor(s, d);
            u[j] += __logf(s);
            const float inv = 1.f / s;
            cp0 = fmaf(e0, inv, cp0);
            cp1 = fmaf(e1, inv, cp1);
            cp2 = fmaf(e2, inv, cp2);
            cp3 = fmaf(e3, inv, cp3);
        }
        *(float4*)&part[w][lane][0] = (float4){cp0, cp1, cp2, cp3};
        __syncthreads();
        if (tid < 256) {
            const int cl = tid >> 2, cq = tid & 3;
            float ss = 0.f;
            #pragma unroll
            for (int w2 = 0; w2 < 16; w2++) ss += part[w2][cl][cq];
            v_s[tid] += __logf(ss);
        }
        __syncthreads();
    }
    const float4 vr = *(const float4*)&v_s[4 * lane];
    #pragma unroll
    for (int j = 0; j < 16; j++) {
        u32 o[4];
        o[0] = packhl(__expf(x[j].x - u[j] - vr.x));
        o[1] = packhl(__expf(x[j].y - u[j] - vr.y));
        o[2] = packhl(__expf(x[j].z - u[j] - vr.z));
        o[3] = packhl(__expf(x[j].w - u[j] - vr.w));
        ((uint4*)(g + (size_t)(w * 16 + j) * 256))[lane] = *(uint4*)o;
    }
}

// ---------------------------------------------------------------------------
// CSR adjacency (built once; graph fixed for the whole launch).
// ---------------------------------------------------------------------------
__global__ __launch_bounds__(256) void zero_deg_kernel(int* __restrict__ deg)
{
    deg[blockIdx.x * 256 + threadIdx.x] = 0;
}

__global__ __launch_bounds__(256) void csr_build_kernel(
    const int* __restrict__ from_idx, const int* __restrict__ to_idx,
    int* __restrict__ deg, u32* __restrict__ adj)
{
    int e = blockIdx.x * 256 + threadIdx.x;
    if (e >= VEe) return;
    int f = from_idx[e], t = to_idx[e];
    int p1 = atomicAdd(&deg[t], 1);
    if (p1 < ADJ_STRIDE) adj[(size_t)t * ADJ_STRIDE + p1] = ((u32)e << 13) | (u32)f;
    int p2 = atomicAdd(&deg[f], 1);
    if (p2 < ADJ_STRIDE) adj[(size_t)f * ADJ_STRIDE + p2] = ((u32)e << 13) | (u32)t;
}

__global__ __launch_bounds__(256) void agg_csr_kernel(
    const u32* __restrict__ P01,
    const u32* __restrict__ ec2,
    const int* __restrict__ deg, const u32* __restrict__ adj,
    u32* __restrict__ agg)
{
    const int n = blockIdx.x;
    const int d = threadIdx.x;
    __shared__ u32 sadj[ADJ_STRIDE];
    __shared__ int sdeg;
    if (d == 0) sdeg = min(deg[n], ADJ_STRIDE);
    if (d < ADJ_STRIDE) sadj[d] = adj[(size_t)n * ADJ_STRIDE + d];
    __syncthreads();
    const int dn = sdeg;
    float a = (float)dn * unpackhl(P01[(size_t)n * 512 + 256 + d]);
    for (int i = 0; i < dn; i++) {
        const u32 en = sadj[i];
        const int e = (int)(en >> 13), pr = (int)(en & 8191u);
        a += unpackhl(ec2[(size_t)e * 256 + d]) + unpackhl(P01[(size_t)pr * 512 + d]);
    }
    agg[(size_t)n * 256 + d] = packhl(a);
}

__global__ void diag_kernel(float* __restrict__ out, float v)
{
    out[threadIdx.x] = v;
}

// score[b] = -sum relu( ffq - plan@ffc ); upd_node + plan packed-hl.
__global__ __launch_bounds__(128) void score_kernel(
    const u32* __restrict__ upd_node, const u32* __restrict__ plan,
    float* __restrict__ out)
{
    const int b = blockIdx.x;
    const int tid = threadIdx.x;
    __shared__ float ffc[48][128];
    __shared__ float pl[64][48];
    __shared__ float red[128];
    for (int c = 0; c < 48; c++)
        ffc[c][tid] = unpackhl(upd_node[(size_t)((2 * b + 1) * 48 + c) * 640 + 512 + tid]);
    for (int idx = tid; idx < 64 * 48; idx += 128) {
        int q = idx / 48, c = idx % 48;
        pl[q][c] = unpackhl(plan[(size_t)b * 4096 + q * 64 + c]);
    }
    __syncthreads();
    float accv = 0.f;
    for (int q = 0; q < 64; q++) {
        float rsum = 0.f;
        #pragma unroll 8
        for (int c = 0; c < 48; c++) rsum = fmaf(pl[q][c], ffc[c][tid], rsum);
        float fq = 0.f;
        if (q < 48) fq = unpackhl(upd_node[(size_t)((2 * b) * 48 + q) * 640 + 512 + tid]);
        accv += fmaxf(fq - rsum, 0.f);
    }
    red[tid] = accv;
    __syncthreads();
    for (int sft = 64; sft > 0; sft >>= 1) {
        if (tid < sft) red[tid] += red[tid + sft];
        __syncthreads();
    }
    if (tid == 0) out[b] = -red[0];
}

// ---------------------------------------------------------------------------
// Workspace layout (floats). Total 66,861,056 floats = 267.44 MB.
// ---------------------------------------------------------------------------
#define OFF_UPD_NODE   0ULL
#define OFF_NODE_STORE 3932160ULL
#define OFF_EDGE_STORE 7077888ULL
#define OFF_ECOMB      32243712ULL
#define OFF_ENC_N      47972352ULL
#define OFF_ENC_E      48758784ULL
#define OFF_N_LA       51904512ULL
#define OFF_WT         52199424ULL
#define OFF_WTL        52547584ULL
#define OFF_ARENA      52895744ULL
#define OFF_DEG        66265088ULL
#define OFF_ADJ        66271232ULL
#define TOTAL_FLOATS   66861056ULL

// bf16 weight sub-offsets (u16 from WT/WTL base)
#define WT_NIW1   0
#define WT_NIW2   65536
#define WT_EIW1   98304
#define WT_EIW2   245760
#define WT_MSG    294912
#define WT_P01    393216
#define WT_NUW1   458752
#define WT_NUW2   557056
#define WT_WSUM   589824
#define WT_ENCN   622592
#define WT_ENCE   626688
#define WT_NS1    630784
#define WT_NS2    647168
#define WT_ES1    655360
#define WT_ES2    688128

#define PK(p) ((u32*)(p))

extern "C" void kernel_launch(void* const* d_in, const int* in_sizes, int n_in,
                              void* d_out, int out_size, void* d_ws, size_t ws_size,
                              hipStream_t stream)
{
    (void)in_sizes; (void)n_in; (void)out_size;
    if (ws_size < TOTAL_FLOATS * sizeof(float)) {
        diag_kernel<<<1, 64, 0, stream>>>((float*)d_out, (float)ws_size);
        return;
    }

    const float* node_features = (const float*)d_in[0];
    const float* edge_features = (const float*)d_in[1];
    const int*   from_idx      = (const int*)d_in[2];
    const int*   to_idx        = (const int*)d_in[3];
    const float* enc_node_W = (const float*)d_in[4];
    const float* enc_node_b = (const float*)d_in[5];
    const float* enc_edge_W = (const float*)d_in[6];
    const float* enc_edge_b = (const float*)d_in[7];
    const float* ni_W1 = (const float*)d_in[8];
    const float* ni_b1 = (const float*)d_in[9];
    const float* ni_W2 = (const float*)d_in[10];
    const float* ni_b2 = (const float*)d_in[11];
    const float* ei_W1 = (const float*)d_in[12];
    const float* ei_b1 = (const float*)d_in[13];
    const float* ei_W2 = (const float*)d_in[14];
    const float* ei_b2 = (const float*)d_in[15];
    const float* msg_W = (const float*)d_in[16];
    const float* msg_b = (const float*)d_in[17];
    const float* nu_W1 = (const float*)d_in[18];
    const float* nu_b1 = (const float*)d_in[19];
    const float* nu_W2 = (const float*)d_in[20];
    const float* nu_b2 = (const float*)d_in[21];
    const float* ns_W1 = (const float*)d_in[22];
    const float* ns_b1 = (const float*)d_in[23];
    const float* ns_W2 = (const float*)d_in[24];
    const float* ns_b2 = (const float*)d_in[25];
    const float* es_W1 = (const float*)d_in[26];
    const float* es_b1 = (const float*)d_in[27];
    const float* es_W2 = (const float*)d_in[28];
    const float* es_b2 = (const float*)d_in[29];

    float* ws = (float*)d_ws;
    float* upd_node   = ws + OFF_UPD_NODE;
    float* node_store = ws + OFF_NODE_STORE;
    float* edge_store = ws + OFF_EDGE_STORE;
    float* ecomb      = ws + OFF_ECOMB;
    float* enc_n      = ws + OFF_ENC_N;
    float* enc_e      = ws + OFF_ENC_E;
    float* n_la       = ws + OFF_N_LA;
    u16* WT  = (u16*)(ws + OFF_WT);
    u16* WTL = (u16*)(ws + OFF_WTL);
    float* arena      = ws + OFF_ARENA;
    int* deg = (int*)(ws + OFF_DEG);
    u32* adj = (u32*)(ws + OFF_ADJ);

    // Phase-A arena carve
    float* A_hidden = arena;                  // VN x 256
    float* A_hcomb  = arena + 1572864;        // VN x 128
    float* A_ehid   = arena + 2359296;        // VE x 384
    float* A_ec2    = arena + 2359296;        // VE x 256 (alias)
    float* A_P01    = arena + 8650752;        // VN x 512
    float* A_aggb   = arena + 11796480;       // VN x 256
    // Phase-B carve
    float* B_Qs       = arena;                // VN x 256 (fp32) -- ping
    float* B_Qs2      = ecomb + (size_t)4 * VEe * 128; // pong (ecomb slot 4: free in phase-B)
    float* B_thid_e   = arena + 8650752;      // VE x 64
    float* B_ttreal_e = arena + 10223616;     // VE x 64 (fp32)
    float* B_ela      = arena + 2359296;      // 64 x 256 x 256 (fp32 -> packed in place)
    float* B_msgs     = arena + 6553600;      // VE x 256
    float* B_thid_n   = arena + 12058624;     // VN x 64
    float* B_ttreal_n = arena + 12451840;     // VN x 64 (fp32)

    // --- one-shot weight prep + CSR adjacency ---
    prep_kernel<<<(696320 + 255) / 256, 256, 0, stream>>>(
        ni_W1, ni_W2, ei_W1, ei_W2, msg_W, nu_W1, nu_W2,
        enc_node_W, enc_edge_W, ns_W1, ns_W2, es_W1, es_W2, WT, WTL);
    zero_deg_kernel<<<VNn / 256, 256, 0, stream>>>(deg);
    csr_build_kernel<<<VEe / 256, 256, 0, stream>>>(from_idx, to_idx, deg, adj);

    // --- encoders (fp32 A, packed out) ---
    gemm_f32_kernel<<<dim3(1, VNn / 128), 256, 0, stream>>>(
        node_features, 32, 32, WT + WT_ENCN, WTL + WT_ENCN, 32, enc_node_b, PK(enc_n), 128, 128);
    gemm_f32_kernel<<<dim3(1, VEe / 128), 256, 0, stream>>>(
        edge_features, 32, 32, WT + WT_ENCE, WTL + WT_ENCE, 32, enc_edge_b, PK(enc_e), 128, 128);

    for (int k = 0; k < 3; k++) {
        for (int p = 1; p <= 5; p++) {
            const bool hs = (k > 0) && (p > 1);
            const u32* hA1 = (p == 1) ? PK(enc_n) : PK(upd_node + (size_t)(p - 2) * 128);
            const int  hlda1 = (p == 1) ? 128 : 640;
            const u32* hA2 = hs ? PK(node_store + (size_t)(p - 2) * 128) : nullptr;
            const int  hK2 = hs ? 128 : 0;
            GemmDesc hcomb1_d = mkDesc(hA1, hlda1, 128, hA2, 512, hK2,
                                       WT + WT_NIW1, WTL + WT_NIW1, 256, ni_b1,
                                       A_hidden, 256, VNn, 256, 256, FL_RELU | FL_OUTPK);
            GemmDesc hcomb2_d = mkDesc(PK(A_hidden), 256, 256, nullptr, 0, 0,
                                       WT + WT_NIW2, WTL + WT_NIW2, 256, ni_b2,
                                       A_hcomb, 128, VNn, 128, 128, FL_OUTPK);
            GemmDesc p01_d = mkDesc(PK(A_hcomb), 128, 128, nullptr, 0, 0,
                                    WT + WT_P01, WTL + WT_P01, 128, nullptr,
                                    A_P01, 512, VNn, 512, 512, FL_OUTPK);

            const bool edge_full = ((k == 0 && p == 1) || (k > 0 && p > 1));
            if (edge_full) {
                const u32* esrc = (k == 0) ? nullptr : PK(edge_store + (size_t)(p - 2) * 256);
                const int  eK2  = (k == 0) ? 0 : 256;
                float* ec_slot = (k == 0) ? ecomb : ecomb + (size_t)(p - 1) * VEe * 128;
                GemmDesc eiW1_d = mkDesc(PK(enc_e), 128, 128, esrc, 1024, eK2,
                                         WT + WT_EIW1, WTL + WT_EIW1, 384, ei_b1,
                                         A_ehid, 384, VEe, 384, 384, FL_RELU | FL_OUTPK);
                GemmDesc eiW2_d = mkDesc(PK(A_ehid), 384, 384, nullptr, 0, 0,
                                         WT + WT_EIW2, WTL + WT_EIW2, 384, ei_b2,
                                         ec_slot, 128, VEe, 128, 128, FL_OUTPK);
                GemmDesc ec2_d = mkDesc(PK(ec_slot), 128, 128, nullptr, 0, 0,
                                        WT + WT_MSG + 256, WTL + WT_MSG + 256, 384, msg_b,
                                        A_ec2, 256, VEe, 256, 256, FL_OUTPK);
                gemm2(stream, eiW1_d, hcomb1_d);
                gemm2(stream, eiW2_d, hcomb2_d);
                gemm2(stream, ec2_d, p01_d);
            } else if (k > 0 && p == 1) {
                GemmDesc ec2_d = mkDesc(PK(ecomb), 128, 128, nullptr, 0, 0,
                                        WT + WT_MSG + 256, WTL + WT_MSG + 256, 384, msg_b,
                                        A_ec2, 256, VEe, 256, 256, FL_OUTPK);
                gemm2(stream, ec2_d, hcomb1_d);
                gemmPK(stream, 64, 64, PK(A_hidden), 256, 256, nullptr, 0, 0,
                       WT + WT_NIW2, WTL + WT_NIW2, 256,
                       ni_b2, A_hcomb, 128, VNn, 128, 128, FL_OUTPK);
                gemmPK(stream, 64, 128, PK(A_hcomb), 128, 128, nullptr, 0, 0,
                       WT + WT_P01, WTL + WT_P01, 128,
                       nullptr, A_P01, 512, VNn, 512, 512, FL_OUTPK);
            } else {
                gemmPK(stream, 64, 64, hA1, hlda1, 128, hA2, 512, hK2,
                       WT + WT_NIW1, WTL + WT_NIW1, 256, ni_b1,
                       A_hidden, 256, VNn, 256, 256, FL_RELU | FL_OUTPK);
                gemmPK(stream, 64, 64, PK(A_hidden), 256, 256, nullptr, 0, 0,
                       WT + WT_NIW2, WTL + WT_NIW2, 256,
                       ni_b2, A_hcomb, 128, VNn, 128, 128, FL_OUTPK);
                gemmPK(stream, 64, 128, PK(A_hcomb), 128, 128, nullptr, 0, 0,
                       WT + WT_P01, WTL + WT_P01, 128,
                       nullptr, A_P01, 512, VNn, 512, 512, FL_OUTPK);
            }
            agg_csr_kernel<<<VNn, 256, 0, stream>>>(PK(A_P01), PK(A_ec2), deg, adj, PK(A_aggb));
            gemmPK(stream, 64, 64, PK(A_hcomb), 128, 128, PK(A_aggb), 256, 256,
                   WT + WT_NUW1, WTL + WT_NUW1, 384,
                   nu_b1, A_hidden, 256, VNn, 256, 256, FL_RELU | FL_OUTPK);
            gemmPK(stream, 64, 64, PK(A_hidden), 256, 256, nullptr, 0, 0,
                   WT + WT_NUW2, WTL + WT_NUW2, 256,
                   nu_b2, upd_node + (size_t)(p - 1) * 128, 640, VNn, 128, 128, FL_OUTPK);
        }
        if (k < 2) {
            // ---- Qs (slot 5) || ns1 ----
            GemmDesc qs_d = mkDesc(PK(upd_node + 512), 640, 128, nullptr, 0, 0,
                                   WT + WT_WSUM, WTL + WT_WSUM, 128, nullptr,
                                   B_Qs, 256, VNn, 256, 256, 0);
            GemmDesc ns1_d = mkDesc(PK(upd_node + 512), 640, 128, nullptr, 0, 0,
                                    WT + WT_NS1, WTL + WT_NS1, 128, ns_b1,
                                    B_thid_n, 64, VNn, 128, 64, FL_RELU | FL_OUTPK);
            gemm2(stream, qs_d, ns1_d);
            // ---- es1 with folded msgs (dedicated kernel) ----
            gemm_es1msgs_kernel<<<dim3(1, VEe / 128), 256, 0, stream>>>(
                PK(A_ec2), B_Qs, from_idx, to_idx,
                WT + WT_ES1, WTL + WT_ES1, es_b1, PK(B_thid_e));
            // ---- es2 || ns2 ----
            GemmDesc es2_d = mkDesc(PK(B_thid_e), 64, 64, nullptr, 0, 0,
                                    WT + WT_ES2, WTL + WT_ES2, 64, es_b2,
                                    B_ttreal_e, 64, VEe, 128, 64, 0);
            GemmDesc ns2_d = mkDesc(PK(B_thid_n), 64, 64, nullptr, 0, 0,
                                    WT + WT_NS2, WTL + WT_NS2, 64, ns_b2,
                                    B_ttreal_n, 64, VNn, 128, 64, 0);
            gemm2(stream, es2_d, ns2_d);
            // ---- merged la: node la+sinkhorn64 (64 blocks) + edge la (1024) ----
            la_fused_kernel<<<64 + 1024, 256, 0, stream>>>(B_ttreal_n, PK(n_la), B_ttreal_e, B_ela);
            sinkhorn256_kernel<<<Bb, 1024, 0, stream>>>(B_ela);
            bgemmDual(stream, PK(n_la), 64, 48, PK(upd_node), 640, PK(node_store), 512, 512);
            // ---- sl loop, Qs ping-pong pipelined under ec2msgs ----
            float* qsbuf[2] = { B_Qs2, B_Qs };
            GemmDesc qs1_d = mkDesc(PK(upd_node), 640, 128, nullptr, 0, 0,
                                    WT + WT_WSUM, WTL + WT_WSUM, 128, nullptr,
                                    qsbuf[0], 256, VNn, 256, 256, 0);
            gemm1(stream, qs1_d);
            for (int sl = 1; sl <= 4; sl++) {
                const size_t ss = (k == 0) ? 0 : (size_t)(sl - 1);
                GemmDesc em_d = mkDesc(PK(ecomb + ss * VEe * 128), 128, 128, nullptr, 0, 0,
                                       WT + WT_MSG + 256, WTL + WT_MSG + 256, 384, msg_b,
                                       B_msgs, 256, VEe, 256, 256, FL_MSGS);
                em_d.qs = qsbuf[(sl - 1) & 1];
                em_d.fidx = from_idx; em_d.tidx = to_idx;
                if (sl < 4) {
                    GemmDesc qsn_d = mkDesc(PK(upd_node + (size_t)sl * 128), 640, 128,
                                            nullptr, 0, 0,
                                            WT + WT_WSUM, WTL + WT_WSUM, 128, nullptr,
                                            qsbuf[sl & 1], 256, VNn, 256, 256, 0);
                    gemm2(stream, em_d, qsn_d);
                } else {
                    gemm1(stream, em_d);
                }
                bgemmDual(stream, PK(B_ela), 256, 192, PK(B_msgs), 256,
                          PK(edge_store + (size_t)(sl - 1) * 256), 1024, 256);
            }
        } else {
            // ---- last k: node transport only ----
            gemmPK(stream, 64, 64, PK(upd_node + 512), 640, 128, nullptr, 0, 0,
                   WT + WT_NS1, WTL + WT_NS1, 128,
                   ns_b1, B_thid_n, 64, VNn, 64, 64, FL_RELU | FL_OUTPK);
            gemmPK(stream, 64, 64, PK(B_thid_n), 64, 64, nullptr, 0, 0,
                   WT + WT_NS2, WTL + WT_NS2, 64,
                   ns_b2, B_ttreal_n, 64, VNn, 64, 64, 0);
            la_fused_kernel<<<64, 256, 0, stream>>>(B_ttreal_n, PK(n_la), B_ttreal_e, B_ela);
        }
    }
    score_kernel<<<Bb, 128, 0, stream>>>(PK(upd_node), PK(n_la), (float*)d_out);
}